// Round 12
// baseline (1093.577 us; speedup 1.0000x reference)
//
#include <hip/hip_runtime.h>
#include <hip/hip_bf16.h>

using bf16 = __hip_bfloat16;
typedef unsigned char u8;
typedef short bf16x8 __attribute__((ext_vector_type(8)));
typedef short bf16x4 __attribute__((ext_vector_type(4)));
typedef float f32x4 __attribute__((ext_vector_type(4)));

#define BNS 0.9999950000374997f   // 1/sqrt(1+1e-5) — folded into weights at prep time
#define MFMA_B16 __builtin_amdgcn_mfma_f32_16x16x32_bf16

__device__ __forceinline__ float b2f(bf16 v){ return __bfloat162float(v); }
__device__ __forceinline__ short f2bs(float v){ bf16 h = __float2bfloat16(v); return *reinterpret_cast<short*>(&h); }
__device__ __forceinline__ float s2f(short s){ union{unsigned u; float f;} x; x.u = ((unsigned)(unsigned short)s) << 16; return x.f; }

__device__ __forceinline__ bf16x8 lds8(const short* p){
    bf16x4 lo = *(const bf16x4*)(p);
    bf16x4 hi = *(const bf16x4*)(p + 4);
    bf16x8 r = {lo[0],lo[1],lo[2],lo[3],hi[0],hi[1],hi[2],hi[3]};
    return r;
}

// ---------------- mask kernels ----------------

__global__ __launch_bounds__(256) void k_mask1(const float* __restrict__ roi, u8* __restrict__ m1, int total){
    int i = blockIdx.x*256 + threadIdx.x;
    if (i < total) m1[i] = (roi[i] > 0.8f) ? 1 : 0;
}

__global__ __launch_bounds__(256) void k_down(const u8* __restrict__ mi, u8* __restrict__ mo,
                                              int IH, int IW, int OH, int OW){
    int p = blockIdx.x*256 + threadIdx.x;
    int n = blockIdx.y;
    if (p >= OH*OW) return;
    int oy = p / OW, ox = p - oy*OW;
    const u8* src = mi + (size_t)n*IH*IW;
    int v = 0;
    #pragma unroll
    for (int ky=0; ky<3; ky++){
        int iy = 2*oy + ky - 1;
        if ((unsigned)iy >= (unsigned)IH) continue;
        #pragma unroll
        for (int kx=0; kx<3; kx++){
            int ix = 2*ox + kx - 1;
            if ((unsigned)ix < (unsigned)IW) v |= src[iy*IW + ix];
        }
    }
    mo[(size_t)n*OH*OW + p] = (u8)v;
}

// ---- weight prep: 6 arrays [32][32][9] fp32 -> bf16 [9][32co][32ci]; BNS folded ----
__global__ __launch_bounds__(256) void k_wprep(const float* __restrict__ w1b,
                                               const float* __restrict__ i2,
                                               const float* __restrict__ l5,
                                               const float* __restrict__ r1a,
                                               const float* __restrict__ w2b,
                                               const float* __restrict__ w2a,
                                               short* __restrict__ dst){
    int a = blockIdx.y;
    const float* src = (a==0)? w1b : (a==1)? i2 : (a==2)? l5 : (a==3)? r1a : (a==4)? w2b : w2a;
    float sc = (a==2) ? 1.0f : BNS;   // l5 stage has no BN scale
    int j = blockIdx.x*256 + threadIdx.x;
    if (j < 9216){
        int co = j/288, r = j%288, ci = r/9, k = r%9;
        dst[a*9216 + k*1024 + co*32 + ci] = f2bs(src[j]*sc);
    }
}

// ---- weight prep 64-wide; BNS folded except l4_sub ----
__global__ __launch_bounds__(256) void k_wprep4(const float* __restrict__ inv4,
                                                const float* __restrict__ w4b,
                                                const float* __restrict__ l4s,
                                                const float* __restrict__ r4w1,
                                                const float* __restrict__ w4a,
                                                short* __restrict__ dst)
{
    int a = blockIdx.y;
    int j = blockIdx.x*256 + threadIdx.x;
    if (a < 2){
        if (j < 36864){
            int co = j/576, r = j%576, ci = r/9, k = r%9;
            const float* s = a ? w4b : inv4;
            dst[a*36864 + k*4096 + co*64 + ci] = f2bs(s[j]*BNS);
        }
    } else if (a < 4){
        if (j < 18432){
            int co = j/576, r = j%576, ci = r/9, k = r%9;
            const float* s = (a==2) ? l4s : r4w1;
            float sc = (a==2) ? 1.0f : BNS;
            dst[73728 + (a-2)*18432 + k*2048 + co*64 + ci] = f2bs(s[j]*sc);
        }
    } else {
        if (j < 18432){
            int co = j/288, r = j%288, ci = r/9, k = r%9;
            dst[110592 + k*2048 + co*32 + ci] = f2bs(w4a[j]*BNS);
        }
    }
}

// ---- misc prep: a=0 w1a im2col (BNS folded); a=1/2 head weights (no BNS) ----
__global__ __launch_bounds__(256) void k_wprep_misc(const float* __restrict__ w1a,
                                                    const float* __restrict__ r1w2,
                                                    const float* __restrict__ r4w2,
                                                    short* __restrict__ d1a,
                                                    short* __restrict__ dh){
    int a = blockIdx.y;
    int j = blockIdx.x*256 + threadIdx.x;
    if (a == 0){
        if (j < 2048){
            int h = j >> 10, r = j & 1023, co = r >> 5, kq = r & 31;
            int q = h*32 + kq;
            d1a[j] = (q < 36) ? f2bs(w1a[co*36 + q]*BNS) : 0;
        }
    } else {
        if (j < 4608){
            int k = j/512, r = j%512, co = r/32, ci = r%32;
            const float* s = (a==1) ? r1w2 : r4w2;
            dh[(a-1)*4608 + j] = (co == 0) ? f2bs(s[ci*9 + k]) : 0;
        }
    }
}

// ---------------- generic MFMA stride-1 conv (round-10 coalesced staging; res prefetch) --
template<int CIN, int COUT, int EPI>
__global__ __launch_bounds__(256) void mconv_s1(const short* __restrict__ in, int H,
                                                const short* __restrict__ wT,
                                                const u8* __restrict__ mask,
                                                const float* __restrict__ res32,
                                                short* __restrict__ out, int tilesX)
{
    const int HW = H*H;
    const int HV = CIN/32, G = COUT/16;
    int tY = blockIdx.x / tilesX, tX = blockIdx.x % tilesX, n = blockIdx.z;
    int y0 = tY*16, x0 = tX*16;

    __shared__ __align__(16) short s_in[HV*11664];
    __shared__ u8 s_m[256];

    int tid = threadIdx.x;
    const short* inN = in + (size_t)n*CIN*HW;
    for (int i = tid; i < CIN*324; i += 256){
        int c = i/324, r = i%324;
        int ry = r/18, rx = r%18;
        int gy = y0-1+ry, gx = x0-1+rx;
        short v = 0;
        if ((unsigned)gy < (unsigned)H && (unsigned)gx < (unsigned)H)
            v = inN[(size_t)c*HW + gy*H + gx];
        s_in[(c>>5)*11664 + r*36 + (c&31)] = v;
    }
    for (int i = tid; i < 256; i += 256){
        int ty = i>>4, tx = i&15;
        s_m[i] = mask[(size_t)n*HW + (y0+ty)*H + x0+tx];
    }

    int wv = tid >> 6, lane = tid & 63;
    int nQ = lane >> 4, nn = lane & 15;

    float pr[4][16];
    if constexpr (EPI == 3){
        #pragma unroll
        for (int u2=0; u2<4; ++u2){
            int nt = u2*4 + wv;
            int p = (y0+nt)*H + x0+nn;
            #pragma unroll
            for (int g=0; g<G; ++g)
                #pragma unroll
                for (int e=0; e<4; ++e){
                    int co = g*16 + nQ*4 + e;
                    pr[u2][g*4+e] = res32[((size_t)(n>>2)*COUT + co)*(size_t)HW + p];
                }
        }
    }
    __syncthreads();

    bf16x8 wa0[9], wa1[9];
    if constexpr (CIN == 32 && COUT == 32){
        #pragma unroll
        for (int k=0;k<9;++k){
            wa0[k] = *(const bf16x8*)(wT + k*1024 + nn*32 + nQ*8);
            wa1[k] = *(const bf16x8*)(wT + k*1024 + (16+nn)*32 + nQ*8);
        }
    }

    #pragma unroll
    for (int u2 = 0; u2 < 4; ++u2){
        int nt = u2*4 + wv;
        int ty = nt, tx = nn;
        f32x4 acc[G];
        #pragma unroll
        for (int g=0;g<G;++g) acc[g] = (f32x4){0,0,0,0};
        #pragma unroll
        for (int ky=0; ky<3; ++ky)
            #pragma unroll
            for (int kx=0; kx<3; ++kx){
                const int k = ky*3+kx;
                #pragma unroll
                for (int h=0; h<HV; ++h){
                    bf16x8 bfr = lds8(s_in + h*11664 + ((ty+ky)*18 + tx+kx)*36 + nQ*8);
                    #pragma unroll
                    for (int g=0; g<G; ++g){
                        bf16x8 a;
                        if constexpr (CIN == 32 && COUT == 32) a = g ? wa1[k] : wa0[k];
                        else a = *(const bf16x8*)(wT + k*COUT*CIN + (g*16+nn)*CIN + h*32 + nQ*8);
                        acc[g] = MFMA_B16(a, bfr, acc[g], 0,0,0);
                    }
                }
            }
        int p = (y0+ty)*H + x0+tx;
        u8 m = s_m[nt*16 + nn];
        short* op = out + (size_t)n*COUT*HW + p;
        #pragma unroll
        for (int g=0; g<G; ++g)
            #pragma unroll
            for (int e=0; e<4; ++e){
                int co = g*16 + nQ*4 + e;
                float a = acc[g][e], o;
                if      (EPI == 0) o = m ? fmaxf(a,0.f) : 0.f;
                else if (EPI == 1) o = m ? (a > 0.f ? a : 0.2f*a) : 0.f;
                else o = m ? fmaxf(a,0.f) + pr[u2][g*4+e] : 0.f;
                op[(size_t)co*HW] = f2bs(o);
            }
    }
}

// ---------------- MFMA COUT=1 head (round-10 staging) ----------------
__global__ __launch_bounds__(256) void mconv_head32(const short* __restrict__ in, int H,
                                                    const short* __restrict__ wTh,  // [9][16][32]
                                                    const float* __restrict__ bias,
                                                    const u8* __restrict__ mask,
                                                    float* __restrict__ out, int tilesX)
{
    const int HW = H*H;
    int tY = blockIdx.x / tilesX, tX = blockIdx.x % tilesX, n = blockIdx.z;
    int y0 = tY*16, x0 = tX*16;

    __shared__ __align__(16) short s_in[11664];
    __shared__ u8 s_m[256];

    int tid = threadIdx.x;
    const short* inN = in + (size_t)n*32*HW;
    for (int i = tid; i < 32*324; i += 256){
        int c = i/324, r = i%324;
        int ry = r/18, rx = r%18;
        int gy = y0-1+ry, gx = x0-1+rx;
        short v = 0;
        if ((unsigned)gy < (unsigned)H && (unsigned)gx < (unsigned)H)
            v = inN[(size_t)c*HW + gy*H + gx];
        s_in[r*36 + c] = v;
    }
    for (int i = tid; i < 256; i += 256){
        int ty = i>>4, tx = i&15;
        s_m[i] = mask[(size_t)n*HW + (y0+ty)*H + x0+tx];
    }
    __syncthreads();

    int wv = tid >> 6, lane = tid & 63;
    int nQ = lane >> 4, nn = lane & 15;
    float bb = bias[0];

    for (int nt = wv; nt < 16; nt += 4){
        int ty = nt, tx = nn;
        f32x4 acc = {0,0,0,0};
        #pragma unroll
        for (int ky=0; ky<3; ++ky)
            #pragma unroll
            for (int kx=0; kx<3; ++kx){
                const int k = ky*3+kx;
                bf16x8 bfr = lds8(s_in + ((ty+ky)*18 + tx+kx)*36 + nQ*8);
                bf16x8 aw = *(const bf16x8*)(wTh + k*512 + nn*32 + nQ*8);
                acc = MFMA_B16(aw, bfr, acc, 0,0,0);
            }
        if (nQ == 0){
            u8 m = s_m[nt*16 + nn];
            int p = (y0+ty)*H + x0+tx;
            out[(size_t)n*HW + p] = m ? acc[0] + bb : -99.f;
        }
    }
}

// ---------------- MFMA stride-2 conv: tile 8x16, CIN=32 (round-10 staging) ----------
template<int COUT>
__global__ __launch_bounds__(256) void mconv_s2m(const short* __restrict__ in, int IH,
                                                 const short* __restrict__ wT,   // [9][COUT][32]
                                                 const u8* __restrict__ mask,
                                                 short* __restrict__ out, int OH, int tilesX)
{
    const int IHW = IH*IH, OHW = OH*OH, G = COUT/16;
    int tY = blockIdx.x / tilesX, tX = blockIdx.x % tilesX, n = blockIdx.z;
    int y0 = tY*8, x0 = tX*16;

    __shared__ __align__(16) short s_in[561*36];
    __shared__ u8 s_m[128];

    int tid = threadIdx.x;
    const short* inN = in + (size_t)n*32*IHW;
    for (int i = tid; i < 32*561; i += 256){
        int c = i/561, r = i%561;
        int ry = r/33, rx = r%33;
        int gy = 2*y0-1+ry, gx = 2*x0-1+rx;
        short v = 0;
        if ((unsigned)gy < (unsigned)IH && (unsigned)gx < (unsigned)IH)
            v = inN[(size_t)c*IHW + gy*IH + gx];
        s_in[r*36 + c] = v;
    }
    for (int i = tid; i < 128; i += 256){
        int ty = i>>4, tx = i&15;
        s_m[i] = mask[(size_t)n*OHW + (y0+ty)*OH + x0+tx];
    }
    __syncthreads();

    int wv = tid >> 6, lane = tid & 63;
    int nQ = lane >> 4, nn = lane & 15;

    for (int nt = wv; nt < 8; nt += 4){
        int ty = nt, tx = nn;
        f32x4 acc[G];
        #pragma unroll
        for (int g=0;g<G;++g) acc[g] = (f32x4){0,0,0,0};
        #pragma unroll
        for (int ky=0; ky<3; ++ky)
            #pragma unroll
            for (int kx=0; kx<3; ++kx){
                const int k = ky*3+kx;
                bf16x8 bfr = lds8(s_in + ((2*ty+ky)*33 + 2*tx+kx)*36 + nQ*8);
                #pragma unroll
                for (int g=0; g<G; ++g){
                    bf16x8 a = *(const bf16x8*)(wT + k*COUT*32 + (g*16+nn)*32 + nQ*8);
                    acc[g] = MFMA_B16(a, bfr, acc[g], 0,0,0);
                }
            }
        int p = (y0+ty)*OH + x0+tx;
        u8 m = s_m[nt*16 + nn];
        short* op = out + (size_t)n*COUT*OHW + p;
        #pragma unroll
        for (int g=0; g<G; ++g)
            #pragma unroll
            for (int e=0; e<4; ++e){
                int co = g*16 + nQ*4 + e;
                float o = m ? fmaxf(acc[g][e],0.f) : 0.f;
                op[(size_t)co*OHW] = f2bs(o);
            }
    }
}

// ---------------- conv1ab v4: im2col MFMA f-stage + MFMA stage-2; tile 16x8 ----------
__global__ __launch_bounds__(256) void conv1ab3(const float* __restrict__ image,
                                                const float* __restrict__ masks,
                                                const u8*  __restrict__ M1,
                                                const short* __restrict__ wT1a,   // [2][32co][32K]
                                                const short* __restrict__ wT1b,   // [9][32co][32ci]
                                                short* __restrict__ fea1)
{
    const int H = 384; const int HW = H*H;
    int tY = blockIdx.x / 48, tX = blockIdx.x % 48, n = blockIdx.z;
    int y0 = tY*16, x0 = tX*8;

    __shared__ float s_inp[4][240];
    __shared__ u8    s_m[240];
    __shared__ __align__(16) short s_ic[180*72];
    short* s_f = s_ic;

    int tid = threadIdx.x;
    for (int i = tid; i < 240; i += 256){
        int ly = i/12, lxx = i%12;
        int gy = y0-2+ly, gx = x0-2+lxx;
        bool inb = ((unsigned)gy < 384u) && ((unsigned)gx < 384u);
        u8 mv = inb ? M1[(size_t)n*HW + gy*H + gx] : 0;
        s_m[i] = mv;
        float mm = (float)mv;
        int p = gy*H + gx;
        #pragma unroll
        for (int c = 0; c < 4; ++c){
            float v = 0.f;
            if (inb) v = (c < 3) ? image[((size_t)(n>>2)*3 + c)*HW + p]
                                 : masks[(size_t)n*HW + p];
            s_inp[c][i] = v*mm;
        }
    }
    __syncthreads();

    for (int i = tid; i < 180*64; i += 256){
        int site = i >> 6, q = i & 63;
        short v = 0;
        if (q < 36){
            int ci = q/9, k = q - ci*9, ky = k/3, kx = k - ky*3;
            int fy = site/10, fx = site - fy*10;
            v = f2bs(s_inp[ci][(fy+ky)*12 + fx+kx]);
        }
        s_ic[site*72 + q] = v;
    }
    __syncthreads();

    int wv = tid >> 6, lane = tid & 63;
    int nQ = lane >> 4, nn = lane & 15;

    f32x4 fr[3][2];
    {
        bf16x8 fa0[2], fa1[2];
        #pragma unroll
        for (int h=0;h<2;++h){
            fa0[h] = *(const bf16x8*)(wT1a + h*1024 + nn*32 + nQ*8);
            fa1[h] = *(const bf16x8*)(wT1a + h*1024 + (16+nn)*32 + nQ*8);
        }
        #pragma unroll
        for (int u=0; u<3; ++u){
            int nt = u*4 + wv;
            int s0 = nt*16 + nn;
            int s = s0 > 179 ? 179 : s0;
            f32x4 a0 = {0,0,0,0}, a1 = {0,0,0,0};
            #pragma unroll
            for (int h=0;h<2;++h){
                bf16x8 bfr = lds8(s_ic + s*72 + h*32 + nQ*8);
                a0 = MFMA_B16(fa0[h], bfr, a0, 0,0,0);
                a1 = MFMA_B16(fa1[h], bfr, a1, 0,0,0);
            }
            fr[u][0] = a0; fr[u][1] = a1;
        }
    }
    __syncthreads();

    #pragma unroll
    for (int u=0; u<3; ++u){
        int nt = u*4 + wv;
        int s0 = nt*16 + nn;
        if (s0 <= 179){
            int fy = s0/10, fx = s0 - fy*10;
            u8 m = s_m[(fy+1)*12 + fx+1];
            #pragma unroll
            for (int g=0; g<2; ++g){
                float r[4];
                #pragma unroll
                for (int e=0; e<4; ++e){
                    float a = fr[u][g][e];
                    r[e] = m ? fmaxf(a,0.f) : 0.f;
                }
                bf16x4 w4 = {f2bs(r[0]),f2bs(r[1]),f2bs(r[2]),f2bs(r[3])};
                *(bf16x4*)(s_f + s0*36 + g*16 + nQ*4) = w4;
            }
        }
    }
    __syncthreads();

    bf16x8 wa0[9], wa1[9];
    #pragma unroll
    for (int k=0;k<9;++k){
        wa0[k] = *(const bf16x8*)(wT1b + k*1024 + nn*32 + nQ*8);
        wa1[k] = *(const bf16x8*)(wT1b + k*1024 + (16+nn)*32 + nQ*8);
    }
    for (int nt = wv; nt < 8; nt += 4){
        int s0 = nt*16 + nn;
        int ty = s0 >> 3, tx = s0 & 7;
        f32x4 acc0 = {0,0,0,0}, acc1 = {0,0,0,0};
        #pragma unroll
        for (int ky=0; ky<3; ++ky)
            #pragma unroll
            for (int kx=0; kx<3; ++kx){
                const int k = ky*3+kx;
                bf16x8 bfr = lds8(s_f + ((ty+ky)*10 + tx+kx)*36 + nQ*8);
                acc0 = MFMA_B16(wa0[k], bfr, acc0, 0,0,0);
                acc1 = MFMA_B16(wa1[k], bfr, acc1, 0,0,0);
            }
        u8 m = s_m[(ty+2)*12 + tx+2];
        short* fp = fea1 + (size_t)n*32*HW + (y0+ty)*H + x0+tx;
        #pragma unroll
        for (int g=0; g<2; ++g)
            #pragma unroll
            for (int e=0; e<4; ++e){
                int co = g*16 + nQ*4 + e;
                float a = g ? acc1[e] : acc0[e];
                float o = m ? fmaxf(a,0.f) : 0.f;
                fp[(size_t)co*HW] = f2bs(o);
            }
    }
}

// ---------------- MFMA layer4 (round-10 staging + fea2 prefetch) ----------------
__global__ __launch_bounds__(256) void fk_l4c(const short* __restrict__ xs,
                                              const short* __restrict__ fea2,
                                              const u8*  __restrict__ M2,
                                              const short* __restrict__ wTi4,
                                              const short* __restrict__ wTl4,
                                              short* __restrict__ u_out)
{
    const int H2 = 192, HW2 = H2*H2, H4 = 96, HW4 = H4*H4;
    int tY = blockIdx.x / 12, tX = blockIdx.x % 12, n = blockIdx.z;
    int y0 = tY*16, x0 = tX*16;
    int uy0 = (y0>>1) - 1, ux0 = (x0>>1) - 1;

    __shared__ __align__(16) short s_xs[2*100*36];
    __shared__ __align__(16) short s_ul[2*324*36];
    __shared__ u8 s_m[324];

    int tid = threadIdx.x;
    const short* xN = xs + (size_t)n*64*HW4;
    for (int i = tid; i < 64*100; i += 256){
        int c = i/100, r = i%100; int ly = r/10, lxx = r%10;
        int gy = uy0+ly, gx = ux0+lxx;
        short v = 0;
        if ((unsigned)gy < 96u && (unsigned)gx < 96u) v = xN[(size_t)c*HW4 + gy*H4 + gx];
        s_xs[(c>>5)*3600 + r*36 + (c&31)] = v;
    }
    for (int i = tid; i < 324; i += 256){
        int ry = i/18, rx = i%18; int gy = y0-1+ry, gx = x0-1+rx;
        s_m[i] = ((unsigned)gy < 192u && (unsigned)gx < 192u) ? M2[(size_t)n*HW2 + gy*H2 + gx] : 0;
    }

    int wv = tid >> 6, lane = tid & 63;
    int nQ = lane >> 4, nn = lane & 15;

    // prefetch fea2 residual (stage B) — always in-bounds
    short pf2[4][8];
    {
        const short* f2N = fea2 + (size_t)n*32*HW2;
        #pragma unroll
        for (int u2=0; u2<4; ++u2){
            int nt = u2*4 + wv;
            int p = (y0+nt)*H2 + x0+nn;
            #pragma unroll
            for (int g=0; g<2; ++g)
                #pragma unroll
                for (int e=0; e<4; ++e){
                    int co = g*16 + nQ*4 + e;
                    pf2[u2][g*4+e] = f2N[(size_t)co*HW2 + p];
                }
        }
    }
    __syncthreads();

    for (int ui = wv; ui < 24; ui += 4){
        int cls = ui/6, nt = ui%6;
        int pY = cls >> 1, pX = cls & 1;
        int s0 = nt*16 + nn;
        int s = s0 > 80 ? 80 : s0;
        int jr = s/9, jc = s%9;
        int ry = 2*jr + pY, rx = 2*jc + pX;
        int gY = y0-1+ry, gX = x0-1+rx;

        int tiy[4], tix[4], twk[4]; int tapN;
        if (pY == 0){
            int iA = ((gY-1)>>1) - uy0, iB = ((gY+1)>>1) - uy0;
            if (pX == 0){
                int jA = ((gX-1)>>1) - ux0, jB = ((gX+1)>>1) - ux0;
                tiy[0]=iA; tix[0]=jA; twk[0]=8;
                tiy[1]=iA; tix[1]=jB; twk[1]=6;
                tiy[2]=iB; tix[2]=jA; twk[2]=2;
                tiy[3]=iB; tix[3]=jB; twk[3]=0; tapN=4;
            } else {
                int j = (gX>>1) - ux0;
                tiy[0]=iA; tix[0]=j; twk[0]=7;
                tiy[1]=iB; tix[1]=j; twk[1]=1; tapN=2;
            }
        } else {
            int i2 = (gY>>1) - uy0;
            if (pX == 0){
                int jA = ((gX-1)>>1) - ux0, jB = ((gX+1)>>1) - ux0;
                tiy[0]=i2; tix[0]=jA; twk[0]=5;
                tiy[1]=i2; tix[1]=jB; twk[1]=3; tapN=2;
            } else {
                tiy[0]=i2; tix[0]=(gX>>1)-ux0; twk[0]=4; tapN=1;
            }
        }

        f32x4 acc[4];
        #pragma unroll
        for (int g=0; g<4; ++g) acc[g] = (f32x4){0,0,0,0};
        for (int t = 0; t < tapN; ++t){
            int off = (tiy[t]*10 + tix[t])*36 + nQ*8;
            bf16x8 xlo = lds8(s_xs + off);
            bf16x8 xhi = lds8(s_xs + 3600 + off);
            const short* wk = wTi4 + twk[t]*4096;
            #pragma unroll
            for (int g=0; g<4; ++g){
                bf16x8 alo = *(const bf16x8*)(wk + (g*16+nn)*64 + nQ*8);
                bf16x8 ahi = *(const bf16x8*)(wk + (g*16+nn)*64 + 32 + nQ*8);
                acc[g] = MFMA_B16(alo, xlo, acc[g], 0,0,0);
                acc[g] = MFMA_B16(ahi, xhi, acc[g], 0,0,0);
            }
        }
        if (s0 <= 80){
            int sidx = ry*18 + rx;
            u8 m = s_m[sidx];
            #pragma unroll
            for (int g=0; g<4; ++g){
                float r[4];
                #pragma unroll
                for (int e=0; e<4; ++e){
                    float a = acc[g][e];
                    r[e] = m ? (a > 0.f ? a : 0.2f*a) : 0.f;
                }
                bf16x4 w4 = {f2bs(r[0]),f2bs(r[1]),f2bs(r[2]),f2bs(r[3])};
                *(bf16x4*)(s_ul + (g>>1)*11664 + sidx*36 + (g&1)*16 + nQ*4) = w4;
            }
        }
    }
    __syncthreads();

    #pragma unroll
    for (int u2 = 0; u2 < 4; ++u2){
        int nt = u2*4 + wv;
        int ty = nt, tx = nn;
        f32x4 acc0 = {0,0,0,0}, acc1 = {0,0,0,0};
        #pragma unroll
        for (int ky=0; ky<3; ++ky)
            #pragma unroll
            for (int kx=0; kx<3; ++kx){
                int k = ky*3+kx;
                int off = ((ty+ky)*18 + tx+kx)*36 + nQ*8;
                bf16x8 vlo = lds8(s_ul + off);
                bf16x8 vhi = lds8(s_ul + 11664 + off);
                const short* wk = wTl4 + k*2048;
                bf16x8 a0lo = *(const bf16x8*)(wk + nn*64 + nQ*8);
                bf16x8 a0hi = *(const bf16x8*)(wk + nn*64 + 32 + nQ*8);
                bf16x8 a1lo = *(const bf16x8*)(wk + (16+nn)*64 + nQ*8);
                bf16x8 a1hi = *(const bf16x8*)(wk + (16+nn)*64 + 32 + nQ*8);
                acc0 = MFMA_B16(a0lo, vlo, acc0, 0,0,0);
                acc0 = MFMA_B16(a0hi, vhi, acc0, 0,0,0);
                acc1 = MFMA_B16(a1lo, vlo, acc1, 0,0,0);
                acc1 = MFMA_B16(a1hi, vhi, acc1, 0,0,0);
            }
        int gy = y0+ty, gx = x0+tx;
        int p = gy*H2 + gx;
        u8 m = s_m[(ty+1)*18 + tx+1];
        short* up = u_out + (size_t)n*32*HW2 + p;
        #pragma unroll
        for (int g=0; g<2; ++g)
            #pragma unroll
            for (int e=0; e<4; ++e){
                int co = g*16 + nQ*4 + e;
                float a = g ? acc1[e] : acc0[e];
                float o = m ? a + s2f(pf2[u2][g*4+e]) : 0.f;
                up[(size_t)co*HW2] = f2bs(o);
            }
    }
}

// ---------------- MFMA back end v7: 16x8 tile; fea1 prefetch; BNS folded ----------------
__global__ __launch_bounds__(256) void fk_back7(const short* __restrict__ u,
                                                const short* __restrict__ fea1,
                                                const u8*  __restrict__ M1,
                                                const short* __restrict__ wTi2,
                                                const short* __restrict__ wTl5,
                                                const short* __restrict__ wTr1a,
                                                const short* __restrict__ wTr1b,  // [9][16][32]
                                                const float* __restrict__ r1_b2,
                                                float* __restrict__ out1)
{
    const int H1 = 384, HW1 = H1*H1, H2 = 192, HW2 = H2*H2;
    int tY = blockIdx.x / 48, tX = blockIdx.x % 48, n = blockIdx.z;
    int y0 = tY*16, x0 = tX*8;
    int uy0 = (y0>>1) - 2, ux0 = (x0>>1) - 2;

    __shared__ __align__(16) short sP0[308*36];
    __shared__ __align__(16) short sP1[240*36];
    __shared__ u8 s_m[308];
    short* s_u  = sP1;
    short* s_vl = sP0;
    short* s_v  = sP1;
    short* s_t1 = sP0;

    int tid = threadIdx.x;
    const short* uN = u + (size_t)n*32*HW2;
    {
        int cc = tid >> 3, r0 = tid & 7;
        const short* src = uN + (size_t)cc*HW2;
        for (int r = r0; r < 96; r += 8){
            int ly = r >> 3, lxx = r & 7;
            int gy = uy0+ly, gx = ux0+lxx;
            short v = 0;
            if ((unsigned)gy < 192u && (unsigned)gx < 192u) v = src[(size_t)gy*H2 + gx];
            s_u[r*36 + cc] = v;
        }
    }
    for (int i = tid; i < 308; i += 256){
        int ry = i/14, rx = i%14; int gy = y0-3+ry, gx = x0-3+rx;
        s_m[i] = ((unsigned)gy < 384u && (unsigned)gx < 384u) ? M1[(size_t)n*HW1 + gy*H1 + gx] : 0;
    }

    int wv = tid >> 6, lane = tid & 63;
    int nQ = lane >> 4, nn = lane & 15;

    // prefetch fea1 residual for stage B
    short pf[4][8];
    {
        #pragma unroll
        for (int u2=0; u2<4; ++u2){
            int nt = u2*4 + wv;
            if (nt < 15){
                int s0 = nt*16 + nn;
                int vy = s0/12, vx = s0%12;
                int gY = y0-2+vy, gX = x0-2+vx;
                int gyc = gY < 0 ? 0 : gY, gxc = gX < 0 ? 0 : gX;
                const short* f1 = fea1 + (size_t)n*32*HW1 + (size_t)gyc*H1 + gxc;
                #pragma unroll
                for (int g=0; g<2; ++g)
                    #pragma unroll
                    for (int e=0; e<4; ++e){
                        int co = g*16 + nQ*4 + e;
                        pf[u2][g*4+e] = f1[(size_t)co*HW1];
                    }
            }
        }
    }
    __syncthreads();

    // ---- stage A: vl[308][32] (BNS folded into wTi2) ----
    for (int ui = wv; ui < 20; ui += 4){
        int cls = ui/5, nt = ui%5;
        int pY = cls >> 1, pX = cls & 1;
        int s0 = nt*16 + nn;
        int s = s0 > 76 ? 76 : s0;
        int jr = s/7, jc = s%7;
        int ry = 2*jr + pY, rx = 2*jc + pX;
        int gY = y0-3+ry, gX = x0-3+rx;

        int tiy[4], tix[4], twk[4]; int tapN;
        if (pY == 0){
            int iA = ((gY-1)>>1) - uy0, iB = ((gY+1)>>1) - uy0;
            if (pX == 0){
                int jA = ((gX-1)>>1) - ux0, jB = ((gX+1)>>1) - ux0;
                tiy[0]=iA; tix[0]=jA; twk[0]=8;
                tiy[1]=iA; tix[1]=jB; twk[1]=6;
                tiy[2]=iB; tix[2]=jA; twk[2]=2;
                tiy[3]=iB; tix[3]=jB; twk[3]=0; tapN=4;
            } else {
                int j = (gX>>1) - ux0;
                tiy[0]=iA; tix[0]=j; twk[0]=7;
                tiy[1]=iB; tix[1]=j; twk[1]=1; tapN=2;
            }
        } else {
            int i2 = (gY>>1) - uy0;
            if (pX == 0){
                int jA = ((gX-1)>>1) - ux0, jB = ((gX+1)>>1) - ux0;
                tiy[0]=i2; tix[0]=jA; twk[0]=5;
                tiy[1]=i2; tix[1]=jB; twk[1]=3; tapN=2;
            } else {
                tiy[0]=i2; tix[0]=(gX>>1)-ux0; twk[0]=4; tapN=1;
            }
        }

        f32x4 acc0 = {0,0,0,0}, acc1 = {0,0,0,0};
        for (int t = 0; t < tapN; ++t){
            bf16x8 bfr = lds8(s_u + (tiy[t]*8 + tix[t])*36 + nQ*8);
            bf16x8 a0 = *(const bf16x8*)(wTi2 + twk[t]*1024 + nn*32 + nQ*8);
            bf16x8 a1 = *(const bf16x8*)(wTi2 + twk[t]*1024 + (16+nn)*32 + nQ*8);
            acc0 = MFMA_B16(a0, bfr, acc0, 0,0,0);
            acc1 = MFMA_B16(a1, bfr, acc1, 0,0,0);
        }
        if (s0 <= 76){
            int sidx = ry*14 + rx;
            u8 m = s_m[sidx];
            float r[8];
            #pragma unroll
            for (int g=0; g<2; ++g)
                #pragma unroll
                for (int e=0; e<4; ++e){
                    float a = g ? acc1[e] : acc0[e];
                    r[g*4+e] = m ? (a > 0.f ? a : 0.2f*a) : 0.f;
                }
            bf16x4 w0 = {f2bs(r[0]),f2bs(r[1]),f2bs(r[2]),f2bs(r[3])};
            bf16x4 w1 = {f2bs(r[4]),f2bs(r[5]),f2bs(r[6]),f2bs(r[7])};
            *(bf16x4*)(s_vl + sidx*36 + nQ*4) = w0;
            *(bf16x4*)(s_vl + sidx*36 + 16 + nQ*4) = w1;
        }
    }
    __syncthreads();

    // ---- stage B: v[240][32] = m ? conv(vl,l5) + fea1(prefetched) : 0 ----
    {
        bf16x8 wb0[9], wb1[9];
        #pragma unroll
        for (int k=0;k<9;++k){
            wb0[k] = *(const bf16x8*)(wTl5 + k*1024 + nn*32 + nQ*8);
            wb1[k] = *(const bf16x8*)(wTl5 + k*1024 + (16+nn)*32 + nQ*8);
        }
        #pragma unroll
        for (int u2 = 0; u2 < 4; ++u2){
            int nt = u2*4 + wv;
            if (nt >= 15) continue;
            int s0 = nt*16 + nn;
            int vy = s0/12, vx = s0%12;
            f32x4 acc0 = {0,0,0,0}, acc1 = {0,0,0,0};
            #pragma unroll
            for (int ky=0; ky<3; ++ky)
                #pragma unroll
                for (int kx=0; kx<3; ++kx){
                    const int k = ky*3+kx;
                    bf16x8 bfr = lds8(s_vl + ((vy+ky)*14 + vx+kx)*36 + nQ*8);
                    acc0 = MFMA_B16(wb0[k], bfr, acc0, 0,0,0);
                    acc1 = MFMA_B16(wb1[k], bfr, acc1, 0,0,0);
                }
            u8 m = s_m[(vy+1)*14 + vx+1];
            float r[8];
            #pragma unroll
            for (int g=0; g<2; ++g)
                #pragma unroll
                for (int e=0; e<4; ++e){
                    float a = g ? acc1[e] : acc0[e];
                    r[g*4+e] = m ? a + s2f(pf[u2][g*4+e]) : 0.f;
                }
            bf16x4 w0 = {f2bs(r[0]),f2bs(r[1]),f2bs(r[2]),f2bs(r[3])};
            bf16x4 w1 = {f2bs(r[4]),f2bs(r[5]),f2bs(r[6]),f2bs(r[7])};
            *(bf16x4*)(s_v + s0*36 + nQ*4) = w0;
            *(bf16x4*)(s_v + s0*36 + 16 + nQ*4) = w1;
        }
    }
    __syncthreads();

    // ---- stage C: t1[180][32] (BNS folded into wTr1a) ----
    {
        bf16x8 wc0[9], wc1[9];
        #pragma unroll
        for (int k=0;k<9;++k){
            wc0[k] = *(const bf16x8*)(wTr1a + k*1024 + nn*32 + nQ*8);
            wc1[k] = *(const bf16x8*)(wTr1a + k*1024 + (16+nn)*32 + nQ*8);
        }
        for (int nt = wv; nt < 12; nt += 4){
            int s0 = nt*16 + nn;
            int s = s0 > 179 ? 179 : s0;
            int qy = s/10, qx = s%10;
            f32x4 acc0 = {0,0,0,0}, acc1 = {0,0,0,0};
            #pragma unroll
            for (int ky=0; ky<3; ++ky)
                #pragma unroll
                for (int kx=0; kx<3; ++kx){
                    const int k = ky*3+kx;
                    bf16x8 bfr = lds8(s_v + ((qy+ky)*12 + qx+kx)*36 + nQ*8);
                    acc0 = MFMA_B16(wc0[k], bfr, acc0, 0,0,0);
                    acc1 = MFMA_B16(wc1[k], bfr, acc1, 0,0,0);
                }
            if (s0 <= 179){
                u8 m = s_m[(qy+2)*14 + qx+2];
                float r[8];
                #pragma unroll
                for (int g=0; g<2; ++g)
                    #pragma unroll
                    for (int e=0; e<4; ++e){
                        float a = g ? acc1[e] : acc0[e];
                        r[g*4+e] = m ? (a > 0.f ? a : 0.2f*a) : 0.f;
                    }
                bf16x4 w0 = {f2bs(r[0]),f2bs(r[1]),f2bs(r[2]),f2bs(r[3])};
                bf16x4 w1 = {f2bs(r[4]),f2bs(r[5]),f2bs(r[6]),f2bs(r[7])};
                *(bf16x4*)(s_t1 + s*36 + nQ*4) = w0;
                *(bf16x4*)(s_t1 + s*36 + 16 + nQ*4) = w1;
            }
        }
    }
    __syncthreads();

    // ---- stage D: out 16x8 via MFMA ----
    {
        float bb = r1_b2[0];
        #pragma unroll
        for (int u2 = 0; u2 < 2; ++u2){
            int nt = u2*4 + wv;
            int s0 = nt*16 + nn;
            int ty = s0 >> 3, tx = s0 & 7;
            f32x4 acc = {0,0,0,0};
            #pragma unroll
            for (int ky=0; ky<3; ++ky)
                #pragma unroll
                for (int kx=0; kx<3; ++kx){
                    const int k = ky*3+kx;
                    bf16x8 bfr = lds8(s_t1 + ((ty+ky)*10 + tx+kx)*36 + nQ*8);
                    bf16x8 aw = *(const bf16x8*)(wTr1b + k*512 + nn*32 + nQ*8);
                    acc = MFMA_B16(aw, bfr, acc, 0,0,0);
                }
            if (nQ == 0){
                u8 m = s_m[(ty+3)*14 + tx+3];
                float o = m ? acc[0] + bb : -99.f;
                out1[(size_t)n*HW1 + (y0+ty)*H1 + (x0+tx)] = o;
            }
        }
    }
}

// ---------------- launch ----------------

extern "C" void kernel_launch(void* const* d_in, const int* in_sizes, int n_in,
                              void* d_out, int out_size, void* d_ws, size_t ws_size,
                              hipStream_t stream)
{
    const float* x      = (const float*)d_in[0];
    const float* image  = (const float*)d_in[1];
    const float* masks  = (const float*)d_in[2];
    const float* roi    = (const float*)d_in[3];
    const float* w1a    = (const float*)d_in[4];
    const float* w1b    = (const float*)d_in[5];
    const float* w2a    = (const float*)d_in[6];
    const float* w2b    = (const float*)d_in[7];
    const float* w4a    = (const float*)d_in[8];
    const float* w4b    = (const float*)d_in[9];
    const float* inv4_w = (const float*)d_in[10];
    const float* l4_sub = (const float*)d_in[11];
    const float* inv2_w = (const float*)d_in[12];
    const float* l5_sub = (const float*)d_in[13];
    const float* r4_w1  = (const float*)d_in[14];
    const float* r4_w2  = (const float*)d_in[15];
    const float* r4_b2  = (const float*)d_in[16];
    const float* r1_w1  = (const float*)d_in[17];
    const float* r1_w2  = (const float*)d_in[18];
    const float* r1_b2  = (const float*)d_in[19];
    float* out = (float*)d_out;

    const int N = 8;
    const int H1 = 384, HW1 = 384*384;
    const int H2 = 192, HW2 = 192*192;
    const int H4 = 96,  HW4 = 96*96;

    char* wsp = (char*)d_ws;
    size_t off = 0;
    auto alloc = [&](size_t bytes) -> char* {
        char* p = wsp + off;
        off += (bytes + 255) & ~(size_t)255;
        return p;
    };
    bf16* FEA1 = (bf16*)alloc((size_t)N*32*HW1*2);
    u8*   M1   = (u8*)alloc((size_t)N*HW1);
    u8*   M2   = (u8*)alloc((size_t)N*HW2);
    u8*   M4   = (u8*)alloc((size_t)N*HW4);
    bf16* FEA2 = (bf16*)alloc((size_t)N*32*HW2*2);
    bf16* XS   = (bf16*)alloc((size_t)N*64*HW4*2);
    bf16* GU   = (bf16*)alloc((size_t)N*32*HW2*2);  // g, then u
    bf16* HT   = (bf16*)alloc((size_t)N*64*HW4*2);  // h, then t_leaky
    short* WT   = (short*)alloc(6*9216*2);          // [w1bT, inv2T, l5T, r1aT, w2bT, w2aT]
    short* WT4  = (short*)alloc((size_t)129024*2);  // [inv4T, w4bT, l4sT, r4w1T, w4aT]
    short* WT1a = (short*)alloc(2048*2);
    short* WTh  = (short*)alloc(2*4608*2);          // [r1_w2 head, r4_w2 head]
    (void)ws_size; (void)in_sizes; (void)n_in; (void)out_size;

    short* wT1b  = WT;
    short* wTi2  = WT + 9216;
    short* wTl5  = WT + 2*9216;
    short* wTr1a = WT + 3*9216;
    short* wT2b  = WT + 4*9216;
    short* wT2a  = WT + 5*9216;
    short* wTi4  = WT4;
    short* wT4b  = WT4 + 36864;
    short* wTl4  = WT4 + 73728;
    short* wTr4a = WT4 + 92160;
    short* wT4a  = WT4 + 110592;
    short* wTr1b = WTh;
    short* wTr4b = WTh + 4608;

    dim3 blk(256);

    // masks + weight prep
    k_mask1<<<dim3((N*HW1 + 255)/256), blk, 0, stream>>>(roi, M1, N*HW1);
    k_down<<<dim3((HW2 + 255)/256, N), blk, 0, stream>>>(M1, M2, H1, H1, H2, H2);
    k_down<<<dim3((HW4 + 255)/256, N), blk, 0, stream>>>(M2, M4, H2, H2, H4, H4);
    k_wprep<<<dim3(36, 6), blk, 0, stream>>>(w1b, inv2_w, l5_sub, r1_w1, w2b, w2a, WT);
    k_wprep4<<<dim3(144, 5), blk, 0, stream>>>(inv4_w, w4b, l4_sub, r4_w1, w4a, WT4);
    k_wprep_misc<<<dim3(18, 3), blk, 0, stream>>>(w1a, r1_w2, r4_w2, WT1a, WTh);

    // front
    conv1ab3<<<dim3(1152, 1, N), blk, 0, stream>>>(image, masks, M1, WT1a, wT1b, (short*)FEA1);
    mconv_s2m<32><<<dim3(288, 1, N), blk, 0, stream>>>((const short*)FEA1, H1, wT2a, M2, (short*)GU, H2, 12);
    mconv_s1<32,32,0><<<dim3(144, 1, N), blk, 0, stream>>>((const short*)GU, H2, wT2b, M2, nullptr, (short*)FEA2, 12);
    mconv_s2m<64><<<dim3(72, 1, N), blk, 0, stream>>>((const short*)FEA2, H2, wT4a, M4, (short*)HT, H4, 6);
    mconv_s1<64,64,3><<<dim3(36, 1, N), blk, 0, stream>>>((const short*)HT, H4, wT4b, M4, x, (short*)XS, 6);

    // refine_OS4
    mconv_s1<64,32,1><<<dim3(36, 1, N), blk, 0, stream>>>((const short*)XS, H4, wTr4a, M4, nullptr, (short*)HT, 6);
    mconv_head32<<<dim3(36, 1, N), blk, 0, stream>>>((const short*)HT, H4, wTr4b, r4_b2, M4, out, 6);

    // layer4 fused (MFMA) -> u
    fk_l4c<<<dim3(144, 1, N), blk, 0, stream>>>((const short*)XS, (const short*)FEA2, M2,
                                                wTi4, wTl4, (short*)GU);

    // MFMA back end -> out1
    fk_back7<<<dim3(1152, 1, N), blk, 0, stream>>>((const short*)GU, (const short*)FEA1, M1,
                                                   wTi2, wTl5, wTr1a, wTr1b, r1_b2,
                                                   out + (size_t)N*HW4);
}

// Round 13
// 1013.815 us; speedup vs baseline: 1.0787x; 1.0787x over previous
//
#include <hip/hip_runtime.h>
#include <hip/hip_bf16.h>

using bf16 = __hip_bfloat16;
typedef unsigned char u8;
typedef short bf16x8 __attribute__((ext_vector_type(8)));
typedef short bf16x4 __attribute__((ext_vector_type(4)));
typedef float f32x4 __attribute__((ext_vector_type(4)));

#define BNS 0.9999950000374997f   // 1/sqrt(1+1e-5) — folded into weights at prep time
#define MFMA_B16 __builtin_amdgcn_mfma_f32_16x16x32_bf16

__device__ __forceinline__ float b2f(bf16 v){ return __bfloat162float(v); }
__device__ __forceinline__ short f2bs(float v){ bf16 h = __float2bfloat16(v); return *reinterpret_cast<short*>(&h); }
__device__ __forceinline__ float s2f(short s){ union{unsigned u; float f;} x; x.u = ((unsigned)(unsigned short)s) << 16; return x.f; }

__device__ __forceinline__ bf16x8 lds8(const short* p){
    bf16x4 lo = *(const bf16x4*)(p);
    bf16x4 hi = *(const bf16x4*)(p + 4);
    bf16x8 r = {lo[0],lo[1],lo[2],lo[3],hi[0],hi[1],hi[2],hi[3]};
    return r;
}

// ---------------- mask kernels ----------------

__global__ __launch_bounds__(256) void k_mask1(const float* __restrict__ roi, u8* __restrict__ m1, int total){
    int i = blockIdx.x*256 + threadIdx.x;
    if (i < total) m1[i] = (roi[i] > 0.8f) ? 1 : 0;
}

__global__ __launch_bounds__(256) void k_down(const u8* __restrict__ mi, u8* __restrict__ mo,
                                              int IH, int IW, int OH, int OW){
    int p = blockIdx.x*256 + threadIdx.x;
    int n = blockIdx.y;
    if (p >= OH*OW) return;
    int oy = p / OW, ox = p - oy*OW;
    const u8* src = mi + (size_t)n*IH*IW;
    int v = 0;
    #pragma unroll
    for (int ky=0; ky<3; ky++){
        int iy = 2*oy + ky - 1;
        if ((unsigned)iy >= (unsigned)IH) continue;
        #pragma unroll
        for (int kx=0; kx<3; kx++){
            int ix = 2*ox + kx - 1;
            if ((unsigned)ix < (unsigned)IW) v |= src[iy*IW + ix];
        }
    }
    mo[(size_t)n*OH*OW + p] = (u8)v;
}

// ---- weight prep: 6 arrays [32][32][9] fp32 -> bf16 [9][32co][32ci]; BNS folded ----
__global__ __launch_bounds__(256) void k_wprep(const float* __restrict__ w1b,
                                               const float* __restrict__ i2,
                                               const float* __restrict__ l5,
                                               const float* __restrict__ r1a,
                                               const float* __restrict__ w2b,
                                               const float* __restrict__ w2a,
                                               short* __restrict__ dst){
    int a = blockIdx.y;
    const float* src = (a==0)? w1b : (a==1)? i2 : (a==2)? l5 : (a==3)? r1a : (a==4)? w2b : w2a;
    float sc = (a==2) ? 1.0f : BNS;   // l5 stage has no BN scale
    int j = blockIdx.x*256 + threadIdx.x;
    if (j < 9216){
        int co = j/288, r = j%288, ci = r/9, k = r%9;
        dst[a*9216 + k*1024 + co*32 + ci] = f2bs(src[j]*sc);
    }
}

// ---- weight prep 64-wide; BNS folded except l4_sub ----
__global__ __launch_bounds__(256) void k_wprep4(const float* __restrict__ inv4,
                                                const float* __restrict__ w4b,
                                                const float* __restrict__ l4s,
                                                const float* __restrict__ r4w1,
                                                const float* __restrict__ w4a,
                                                short* __restrict__ dst)
{
    int a = blockIdx.y;
    int j = blockIdx.x*256 + threadIdx.x;
    if (a < 2){
        if (j < 36864){
            int co = j/576, r = j%576, ci = r/9, k = r%9;
            const float* s = a ? w4b : inv4;
            dst[a*36864 + k*4096 + co*64 + ci] = f2bs(s[j]*BNS);
        }
    } else if (a < 4){
        if (j < 18432){
            int co = j/576, r = j%576, ci = r/9, k = r%9;
            const float* s = (a==2) ? l4s : r4w1;
            float sc = (a==2) ? 1.0f : BNS;
            dst[73728 + (a-2)*18432 + k*2048 + co*64 + ci] = f2bs(s[j]*sc);
        }
    } else {
        if (j < 18432){
            int co = j/288, r = j%288, ci = r/9, k = r%9;
            dst[110592 + k*2048 + co*32 + ci] = f2bs(w4a[j]*BNS);
        }
    }
}

// ---- misc prep: a=0 w1a im2col (BNS folded); a=1/2 head weights (no BNS) ----
__global__ __launch_bounds__(256) void k_wprep_misc(const float* __restrict__ w1a,
                                                    const float* __restrict__ r1w2,
                                                    const float* __restrict__ r4w2,
                                                    short* __restrict__ d1a,
                                                    short* __restrict__ dh){
    int a = blockIdx.y;
    int j = blockIdx.x*256 + threadIdx.x;
    if (a == 0){
        if (j < 2048){
            int h = j >> 10, r = j & 1023, co = r >> 5, kq = r & 31;
            int q = h*32 + kq;
            d1a[j] = (q < 36) ? f2bs(w1a[co*36 + q]*BNS) : 0;
        }
    } else {
        if (j < 4608){
            int k = j/512, r = j%512, co = r/32, ci = r%32;
            const float* s = (a==1) ? r1w2 : r4w2;
            dh[(a-1)*4608 + j] = (co == 0) ? f2bs(s[ci*9 + k]) : 0;
        }
    }
}

// ---------------- generic MFMA stride-1 conv (round-10 form; epilogue res load) --------
template<int CIN, int COUT, int EPI>
__global__ __launch_bounds__(256) void mconv_s1(const short* __restrict__ in, int H,
                                                const short* __restrict__ wT,
                                                const u8* __restrict__ mask,
                                                const float* __restrict__ res32,
                                                short* __restrict__ out, int tilesX)
{
    const int HW = H*H;
    const int HV = CIN/32, G = COUT/16;
    int tY = blockIdx.x / tilesX, tX = blockIdx.x % tilesX, n = blockIdx.z;
    int y0 = tY*16, x0 = tX*16;

    __shared__ __align__(16) short s_in[HV*11664];
    __shared__ u8 s_m[256];

    int tid = threadIdx.x;
    const short* inN = in + (size_t)n*CIN*HW;
    for (int i = tid; i < CIN*324; i += 256){
        int c = i/324, r = i%324;
        int ry = r/18, rx = r%18;
        int gy = y0-1+ry, gx = x0-1+rx;
        short v = 0;
        if ((unsigned)gy < (unsigned)H && (unsigned)gx < (unsigned)H)
            v = inN[(size_t)c*HW + gy*H + gx];
        s_in[(c>>5)*11664 + r*36 + (c&31)] = v;
    }
    for (int i = tid; i < 256; i += 256){
        int ty = i>>4, tx = i&15;
        s_m[i] = mask[(size_t)n*HW + (y0+ty)*H + x0+tx];
    }
    __syncthreads();

    int wv = tid >> 6, lane = tid & 63;
    int nQ = lane >> 4, nn = lane & 15;

    bf16x8 wa0[9], wa1[9];
    if constexpr (CIN == 32 && COUT == 32){
        #pragma unroll
        for (int k=0;k<9;++k){
            wa0[k] = *(const bf16x8*)(wT + k*1024 + nn*32 + nQ*8);
            wa1[k] = *(const bf16x8*)(wT + k*1024 + (16+nn)*32 + nQ*8);
        }
    }

    #pragma unroll
    for (int u2 = 0; u2 < 4; ++u2){
        int nt = u2*4 + wv;
        int ty = nt, tx = nn;
        f32x4 acc[G];
        #pragma unroll
        for (int g=0;g<G;++g) acc[g] = (f32x4){0,0,0,0};
        #pragma unroll
        for (int ky=0; ky<3; ++ky)
            #pragma unroll
            for (int kx=0; kx<3; ++kx){
                const int k = ky*3+kx;
                #pragma unroll
                for (int h=0; h<HV; ++h){
                    bf16x8 bfr = lds8(s_in + h*11664 + ((ty+ky)*18 + tx+kx)*36 + nQ*8);
                    #pragma unroll
                    for (int g=0; g<G; ++g){
                        bf16x8 a;
                        if constexpr (CIN == 32 && COUT == 32) a = g ? wa1[k] : wa0[k];
                        else a = *(const bf16x8*)(wT + k*COUT*CIN + (g*16+nn)*CIN + h*32 + nQ*8);
                        acc[g] = MFMA_B16(a, bfr, acc[g], 0,0,0);
                    }
                }
            }
        int p = (y0+ty)*H + x0+tx;
        u8 m = s_m[nt*16 + nn];
        short* op = out + (size_t)n*COUT*HW + p;
        #pragma unroll
        for (int g=0; g<G; ++g)
            #pragma unroll
            for (int e=0; e<4; ++e){
                int co = g*16 + nQ*4 + e;
                float a = acc[g][e], o;
                if      (EPI == 0) o = m ? fmaxf(a,0.f) : 0.f;
                else if (EPI == 1) o = m ? (a > 0.f ? a : 0.2f*a) : 0.f;
                else o = m ? fmaxf(a,0.f) + res32[((size_t)(n>>2)*COUT + co)*(size_t)HW + p] : 0.f;
                op[(size_t)co*HW] = f2bs(o);
            }
    }
}

// ---------------- MFMA COUT=1 head (round-10 staging) ----------------
__global__ __launch_bounds__(256) void mconv_head32(const short* __restrict__ in, int H,
                                                    const short* __restrict__ wTh,  // [9][16][32]
                                                    const float* __restrict__ bias,
                                                    const u8* __restrict__ mask,
                                                    float* __restrict__ out, int tilesX)
{
    const int HW = H*H;
    int tY = blockIdx.x / tilesX, tX = blockIdx.x % tilesX, n = blockIdx.z;
    int y0 = tY*16, x0 = tX*16;

    __shared__ __align__(16) short s_in[11664];
    __shared__ u8 s_m[256];

    int tid = threadIdx.x;
    const short* inN = in + (size_t)n*32*HW;
    for (int i = tid; i < 32*324; i += 256){
        int c = i/324, r = i%324;
        int ry = r/18, rx = r%18;
        int gy = y0-1+ry, gx = x0-1+rx;
        short v = 0;
        if ((unsigned)gy < (unsigned)H && (unsigned)gx < (unsigned)H)
            v = inN[(size_t)c*HW + gy*H + gx];
        s_in[r*36 + c] = v;
    }
    for (int i = tid; i < 256; i += 256){
        int ty = i>>4, tx = i&15;
        s_m[i] = mask[(size_t)n*HW + (y0+ty)*H + x0+tx];
    }
    __syncthreads();

    int wv = tid >> 6, lane = tid & 63;
    int nQ = lane >> 4, nn = lane & 15;
    float bb = bias[0];

    for (int nt = wv; nt < 16; nt += 4){
        int ty = nt, tx = nn;
        f32x4 acc = {0,0,0,0};
        #pragma unroll
        for (int ky=0; ky<3; ++ky)
            #pragma unroll
            for (int kx=0; kx<3; ++kx){
                const int k = ky*3+kx;
                bf16x8 bfr = lds8(s_in + ((ty+ky)*18 + tx+kx)*36 + nQ*8);
                bf16x8 aw = *(const bf16x8*)(wTh + k*512 + nn*32 + nQ*8);
                acc = MFMA_B16(aw, bfr, acc, 0,0,0);
            }
        if (nQ == 0){
            u8 m = s_m[nt*16 + nn];
            int p = (y0+ty)*H + x0+tx;
            out[(size_t)n*HW + p] = m ? acc[0] + bb : -99.f;
        }
    }
}

// ---------------- MFMA stride-2 conv: tile 8x16, CIN=32; IL = input interleaved --------
template<int COUT, bool IL>
__global__ __launch_bounds__(256) void mconv_s2m(const short* __restrict__ in, int IH,
                                                 const short* __restrict__ wT,   // [9][COUT][32]
                                                 const u8* __restrict__ mask,
                                                 short* __restrict__ out, int OH, int tilesX)
{
    const int IHW = IH*IH, OHW = OH*OH, G = COUT/16;
    int tY = blockIdx.x / tilesX, tX = blockIdx.x % tilesX, n = blockIdx.z;
    int y0 = tY*8, x0 = tX*16;

    __shared__ __align__(16) short s_in[561*36];
    __shared__ u8 s_m[128];

    int tid = threadIdx.x;
    const short* inN = in + (size_t)n*32*IHW;
    for (int i = tid; i < 32*561; i += 256){
        int c, r;
        if constexpr (IL){ c = i & 31; r = i >> 5; }
        else             { c = i/561;  r = i%561; }
        int ry = r/33, rx = r%33;
        int gy = 2*y0-1+ry, gx = 2*x0-1+rx;
        short v = 0;
        if ((unsigned)gy < (unsigned)IH && (unsigned)gx < (unsigned)IH){
            if constexpr (IL) v = inN[((size_t)gy*IH + gx)*32 + c];
            else              v = inN[(size_t)c*IHW + (size_t)gy*IH + gx];
        }
        s_in[r*36 + c] = v;
    }
    for (int i = tid; i < 128; i += 256){
        int ty = i>>4, tx = i&15;
        s_m[i] = mask[(size_t)n*OHW + (y0+ty)*OH + x0+tx];
    }
    __syncthreads();

    int wv = tid >> 6, lane = tid & 63;
    int nQ = lane >> 4, nn = lane & 15;

    for (int nt = wv; nt < 8; nt += 4){
        int ty = nt, tx = nn;
        f32x4 acc[G];
        #pragma unroll
        for (int g=0;g<G;++g) acc[g] = (f32x4){0,0,0,0};
        #pragma unroll
        for (int ky=0; ky<3; ++ky)
            #pragma unroll
            for (int kx=0; kx<3; ++kx){
                const int k = ky*3+kx;
                bf16x8 bfr = lds8(s_in + ((2*ty+ky)*33 + 2*tx+kx)*36 + nQ*8);
                #pragma unroll
                for (int g=0; g<G; ++g){
                    bf16x8 a = *(const bf16x8*)(wT + k*COUT*32 + (g*16+nn)*32 + nQ*8);
                    acc[g] = MFMA_B16(a, bfr, acc[g], 0,0,0);
                }
            }
        int p = (y0+ty)*OH + x0+tx;
        u8 m = s_m[nt*16 + nn];
        short* op = out + (size_t)n*COUT*OHW + p;
        #pragma unroll
        for (int g=0; g<G; ++g)
            #pragma unroll
            for (int e=0; e<4; ++e){
                int co = g*16 + nQ*4 + e;
                float o = m ? fmaxf(acc[g][e],0.f) : 0.f;
                op[(size_t)co*OHW] = f2bs(o);
            }
    }
}

// ---------------- conv1ab v5: im2col MFMA f-stage + MFMA stage-2; fea1 interleaved ----
__global__ __launch_bounds__(256) void conv1ab3(const float* __restrict__ image,
                                                const float* __restrict__ masks,
                                                const u8*  __restrict__ M1,
                                                const short* __restrict__ wT1a,   // [2][32co][32K]
                                                const short* __restrict__ wT1b,   // [9][32co][32ci]
                                                short* __restrict__ fea1)         // [N][HW][32]
{
    const int H = 384; const int HW = H*H;
    int tY = blockIdx.x / 48, tX = blockIdx.x % 48, n = blockIdx.z;
    int y0 = tY*16, x0 = tX*8;

    __shared__ float s_inp[4][240];
    __shared__ u8    s_m[240];
    __shared__ __align__(16) short s_ic[180*72];
    short* s_f = s_ic;

    int tid = threadIdx.x;
    for (int i = tid; i < 240; i += 256){
        int ly = i/12, lxx = i%12;
        int gy = y0-2+ly, gx = x0-2+lxx;
        bool inb = ((unsigned)gy < 384u) && ((unsigned)gx < 384u);
        u8 mv = inb ? M1[(size_t)n*HW + gy*H + gx] : 0;
        s_m[i] = mv;
        float mm = (float)mv;
        int p = gy*H + gx;
        #pragma unroll
        for (int c = 0; c < 4; ++c){
            float v = 0.f;
            if (inb) v = (c < 3) ? image[((size_t)(n>>2)*3 + c)*HW + p]
                                 : masks[(size_t)n*HW + p];
            s_inp[c][i] = v*mm;
        }
    }
    __syncthreads();

    for (int i = tid; i < 180*64; i += 256){
        int site = i >> 6, q = i & 63;
        short v = 0;
        if (q < 36){
            int ci = q/9, k = q - ci*9, ky = k/3, kx = k - ky*3;
            int fy = site/10, fx = site - fy*10;
            v = f2bs(s_inp[ci][(fy+ky)*12 + fx+kx]);
        }
        s_ic[site*72 + q] = v;
    }
    __syncthreads();

    int wv = tid >> 6, lane = tid & 63;
    int nQ = lane >> 4, nn = lane & 15;

    f32x4 fr[3][2];
    {
        bf16x8 fa0[2], fa1[2];
        #pragma unroll
        for (int h=0;h<2;++h){
            fa0[h] = *(const bf16x8*)(wT1a + h*1024 + nn*32 + nQ*8);
            fa1[h] = *(const bf16x8*)(wT1a + h*1024 + (16+nn)*32 + nQ*8);
        }
        #pragma unroll
        for (int u=0; u<3; ++u){
            int nt = u*4 + wv;
            int s0 = nt*16 + nn;
            int s = s0 > 179 ? 179 : s0;
            f32x4 a0 = {0,0,0,0}, a1 = {0,0,0,0};
            #pragma unroll
            for (int h=0;h<2;++h){
                bf16x8 bfr = lds8(s_ic + s*72 + h*32 + nQ*8);
                a0 = MFMA_B16(fa0[h], bfr, a0, 0,0,0);
                a1 = MFMA_B16(fa1[h], bfr, a1, 0,0,0);
            }
            fr[u][0] = a0; fr[u][1] = a1;
        }
    }
    __syncthreads();

    #pragma unroll
    for (int u=0; u<3; ++u){
        int nt = u*4 + wv;
        int s0 = nt*16 + nn;
        if (s0 <= 179){
            int fy = s0/10, fx = s0 - fy*10;
            u8 m = s_m[(fy+1)*12 + fx+1];
            #pragma unroll
            for (int g=0; g<2; ++g){
                float r[4];
                #pragma unroll
                for (int e=0; e<4; ++e){
                    float a = fr[u][g][e];
                    r[e] = m ? fmaxf(a,0.f) : 0.f;
                }
                bf16x4 w4 = {f2bs(r[0]),f2bs(r[1]),f2bs(r[2]),f2bs(r[3])};
                *(bf16x4*)(s_f + s0*36 + g*16 + nQ*4) = w4;
            }
        }
    }
    __syncthreads();

    bf16x8 wa0[9], wa1[9];
    #pragma unroll
    for (int k=0;k<9;++k){
        wa0[k] = *(const bf16x8*)(wT1b + k*1024 + nn*32 + nQ*8);
        wa1[k] = *(const bf16x8*)(wT1b + k*1024 + (16+nn)*32 + nQ*8);
    }
    for (int nt = wv; nt < 8; nt += 4){
        int s0 = nt*16 + nn;
        int ty = s0 >> 3, tx = s0 & 7;
        f32x4 acc0 = {0,0,0,0}, acc1 = {0,0,0,0};
        #pragma unroll
        for (int ky=0; ky<3; ++ky)
            #pragma unroll
            for (int kx=0; kx<3; ++kx){
                const int k = ky*3+kx;
                bf16x8 bfr = lds8(s_f + ((ty+ky)*10 + tx+kx)*36 + nQ*8);
                acc0 = MFMA_B16(wa0[k], bfr, acc0, 0,0,0);
                acc1 = MFMA_B16(wa1[k], bfr, acc1, 0,0,0);
            }
        u8 m = s_m[(ty+2)*12 + tx+2];
        // interleaved write: [site][co], two b64 stores
        short* fp = fea1 + ((size_t)n*HW + (size_t)(y0+ty)*H + (x0+tx))*32;
        #pragma unroll
        for (int g=0; g<2; ++g){
            float r[4];
            #pragma unroll
            for (int e=0; e<4; ++e){
                float a = g ? acc1[e] : acc0[e];
                r[e] = m ? fmaxf(a,0.f) : 0.f;
            }
            bf16x4 w4 = {f2bs(r[0]),f2bs(r[1]),f2bs(r[2]),f2bs(r[3])};
            *(bf16x4*)(fp + g*16 + nQ*4) = w4;
        }
    }
}

// ---------------- MFMA layer4 (round-10 staging + fea2 prefetch) ----------------
__global__ __launch_bounds__(256) void fk_l4c(const short* __restrict__ xs,
                                              const short* __restrict__ fea2,
                                              const u8*  __restrict__ M2,
                                              const short* __restrict__ wTi4,
                                              const short* __restrict__ wTl4,
                                              short* __restrict__ u_out)
{
    const int H2 = 192, HW2 = H2*H2, H4 = 96, HW4 = H4*H4;
    int tY = blockIdx.x / 12, tX = blockIdx.x % 12, n = blockIdx.z;
    int y0 = tY*16, x0 = tX*16;
    int uy0 = (y0>>1) - 1, ux0 = (x0>>1) - 1;

    __shared__ __align__(16) short s_xs[2*100*36];
    __shared__ __align__(16) short s_ul[2*324*36];
    __shared__ u8 s_m[324];

    int tid = threadIdx.x;
    const short* xN = xs + (size_t)n*64*HW4;
    for (int i = tid; i < 64*100; i += 256){
        int c = i/100, r = i%100; int ly = r/10, lxx = r%10;
        int gy = uy0+ly, gx = ux0+lxx;
        short v = 0;
        if ((unsigned)gy < 96u && (unsigned)gx < 96u) v = xN[(size_t)c*HW4 + gy*H4 + gx];
        s_xs[(c>>5)*3600 + r*36 + (c&31)] = v;
    }
    for (int i = tid; i < 324; i += 256){
        int ry = i/18, rx = i%18; int gy = y0-1+ry, gx = x0-1+rx;
        s_m[i] = ((unsigned)gy < 192u && (unsigned)gx < 192u) ? M2[(size_t)n*HW2 + gy*H2 + gx] : 0;
    }

    int wv = tid >> 6, lane = tid & 63;
    int nQ = lane >> 4, nn = lane & 15;

    // prefetch fea2 residual (stage B) — always in-bounds
    short pf2[4][8];
    {
        const short* f2N = fea2 + (size_t)n*32*HW2;
        #pragma unroll
        for (int u2=0; u2<4; ++u2){
            int nt = u2*4 + wv;
            int p = (y0+nt)*H2 + x0+nn;
            #pragma unroll
            for (int g=0; g<2; ++g)
                #pragma unroll
                for (int e=0; e<4; ++e){
                    int co = g*16 + nQ*4 + e;
                    pf2[u2][g*4+e] = f2N[(size_t)co*HW2 + p];
                }
        }
    }
    __syncthreads();

    for (int ui = wv; ui < 24; ui += 4){
        int cls = ui/6, nt = ui%6;
        int pY = cls >> 1, pX = cls & 1;
        int s0 = nt*16 + nn;
        int s = s0 > 80 ? 80 : s0;
        int jr = s/9, jc = s%9;
        int ry = 2*jr + pY, rx = 2*jc + pX;
        int gY = y0-1+ry, gX = x0-1+rx;

        int tiy[4], tix[4], twk[4]; int tapN;
        if (pY == 0){
            int iA = ((gY-1)>>1) - uy0, iB = ((gY+1)>>1) - uy0;
            if (pX == 0){
                int jA = ((gX-1)>>1) - ux0, jB = ((gX+1)>>1) - ux0;
                tiy[0]=iA; tix[0]=jA; twk[0]=8;
                tiy[1]=iA; tix[1]=jB; twk[1]=6;
                tiy[2]=iB; tix[2]=jA; twk[2]=2;
                tiy[3]=iB; tix[3]=jB; twk[3]=0; tapN=4;
            } else {
                int j = (gX>>1) - ux0;
                tiy[0]=iA; tix[0]=j; twk[0]=7;
                tiy[1]=iB; tix[1]=j; twk[1]=1; tapN=2;
            }
        } else {
            int i2 = (gY>>1) - uy0;
            if (pX == 0){
                int jA = ((gX-1)>>1) - ux0, jB = ((gX+1)>>1) - ux0;
                tiy[0]=i2; tix[0]=jA; twk[0]=5;
                tiy[1]=i2; tix[1]=jB; twk[1]=3; tapN=2;
            } else {
                tiy[0]=i2; tix[0]=(gX>>1)-ux0; twk[0]=4; tapN=1;
            }
        }

        f32x4 acc[4];
        #pragma unroll
        for (int g=0; g<4; ++g) acc[g] = (f32x4){0,0,0,0};
        for (int t = 0; t < tapN; ++t){
            int off = (tiy[t]*10 + tix[t])*36 + nQ*8;
            bf16x8 xlo = lds8(s_xs + off);
            bf16x8 xhi = lds8(s_xs + 3600 + off);
            const short* wk = wTi4 + twk[t]*4096;
            #pragma unroll
            for (int g=0; g<4; ++g){
                bf16x8 alo = *(const bf16x8*)(wk + (g*16+nn)*64 + nQ*8);
                bf16x8 ahi = *(const bf16x8*)(wk + (g*16+nn)*64 + 32 + nQ*8);
                acc[g] = MFMA_B16(alo, xlo, acc[g], 0,0,0);
                acc[g] = MFMA_B16(ahi, xhi, acc[g], 0,0,0);
            }
        }
        if (s0 <= 80){
            int sidx = ry*18 + rx;
            u8 m = s_m[sidx];
            #pragma unroll
            for (int g=0; g<4; ++g){
                float r[4];
                #pragma unroll
                for (int e=0; e<4; ++e){
                    float a = acc[g][e];
                    r[e] = m ? (a > 0.f ? a : 0.2f*a) : 0.f;
                }
                bf16x4 w4 = {f2bs(r[0]),f2bs(r[1]),f2bs(r[2]),f2bs(r[3])};
                *(bf16x4*)(s_ul + (g>>1)*11664 + sidx*36 + (g&1)*16 + nQ*4) = w4;
            }
        }
    }
    __syncthreads();

    #pragma unroll
    for (int u2 = 0; u2 < 4; ++u2){
        int nt = u2*4 + wv;
        int ty = nt, tx = nn;
        f32x4 acc0 = {0,0,0,0}, acc1 = {0,0,0,0};
        #pragma unroll
        for (int ky=0; ky<3; ++ky)
            #pragma unroll
            for (int kx=0; kx<3; ++kx){
                int k = ky*3+kx;
                int off = ((ty+ky)*18 + tx+kx)*36 + nQ*8;
                bf16x8 vlo = lds8(s_ul + off);
                bf16x8 vhi = lds8(s_ul + 11664 + off);
                const short* wk = wTl4 + k*2048;
                bf16x8 a0lo = *(const bf16x8*)(wk + nn*64 + nQ*8);
                bf16x8 a0hi = *(const bf16x8*)(wk + nn*64 + 32 + nQ*8);
                bf16x8 a1lo = *(const bf16x8*)(wk + (16+nn)*64 + nQ*8);
                bf16x8 a1hi = *(const bf16x8*)(wk + (16+nn)*64 + 32 + nQ*8);
                acc0 = MFMA_B16(a0lo, vlo, acc0, 0,0,0);
                acc0 = MFMA_B16(a0hi, vhi, acc0, 0,0,0);
                acc1 = MFMA_B16(a1lo, vlo, acc1, 0,0,0);
                acc1 = MFMA_B16(a1hi, vhi, acc1, 0,0,0);
            }
        int gy = y0+ty, gx = x0+tx;
        int p = gy*H2 + gx;
        u8 m = s_m[(ty+1)*18 + tx+1];
        short* up = u_out + (size_t)n*32*HW2 + p;
        #pragma unroll
        for (int g=0; g<2; ++g)
            #pragma unroll
            for (int e=0; e<4; ++e){
                int co = g*16 + nQ*4 + e;
                float a = g ? acc1[e] : acc0[e];
                float o = m ? a + s2f(pf2[u2][g*4+e]) : 0.f;
                up[(size_t)co*HW2] = f2bs(o);
            }
    }
}

// ---------------- MFMA back end v8: 16x8 tile; vectorized interleaved fea1 prefetch ----
__global__ __launch_bounds__(256) void fk_back8(const short* __restrict__ u,
                                                const short* __restrict__ fea1,   // [N][HW1][32]
                                                const u8*  __restrict__ M1,
                                                const short* __restrict__ wTi2,
                                                const short* __restrict__ wTl5,
                                                const short* __restrict__ wTr1a,
                                                const short* __restrict__ wTr1b,  // [9][16][32]
                                                const float* __restrict__ r1_b2,
                                                float* __restrict__ out1)
{
    const int H1 = 384, HW1 = H1*H1, H2 = 192, HW2 = H2*H2;
    int tY = blockIdx.x / 48, tX = blockIdx.x % 48, n = blockIdx.z;
    int y0 = tY*16, x0 = tX*8;
    int uy0 = (y0>>1) - 2, ux0 = (x0>>1) - 2;

    __shared__ __align__(16) short sP0[308*36];
    __shared__ __align__(16) short sP1[240*36];
    __shared__ u8 s_m[308];
    short* s_u  = sP1;
    short* s_vl = sP0;
    short* s_v  = sP1;
    short* s_t1 = sP0;

    int tid = threadIdx.x;
    const short* uN = u + (size_t)n*32*HW2;
    {
        int cc = tid >> 3, r0 = tid & 7;
        const short* src = uN + (size_t)cc*HW2;
        for (int r = r0; r < 96; r += 8){
            int ly = r >> 3, lxx = r & 7;
            int gy = uy0+ly, gx = ux0+lxx;
            short v = 0;
            if ((unsigned)gy < 192u && (unsigned)gx < 192u) v = src[(size_t)gy*H2 + gx];
            s_u[r*36 + cc] = v;
        }
    }
    for (int i = tid; i < 308; i += 256){
        int ry = i/14, rx = i%14; int gy = y0-3+ry, gx = x0-3+rx;
        s_m[i] = ((unsigned)gy < 384u && (unsigned)gx < 384u) ? M1[(size_t)n*HW1 + gy*H1 + gx] : 0;
    }

    int wv = tid >> 6, lane = tid & 63;
    int nQ = lane >> 4, nn = lane & 15;

    // prefetch fea1 residual (interleaved layout): two b64 loads per unit, clamped
    bf16x4 pf[4][2];
    {
        #pragma unroll
        for (int u2=0; u2<4; ++u2){
            int nt = u2*4 + wv;
            if (nt < 15){
                int s0 = nt*16 + nn;
                int vy = s0/12, vx = s0%12;
                int gY = y0-2+vy, gX = x0-2+vx;
                int gyc = gY < 0 ? 0 : (gY > 383 ? 383 : gY);
                int gxc = gX < 0 ? 0 : (gX > 383 ? 383 : gX);
                const short* f1 = fea1 + ((size_t)n*HW1 + (size_t)gyc*H1 + gxc)*32;
                pf[u2][0] = *(const bf16x4*)(f1 + nQ*4);
                pf[u2][1] = *(const bf16x4*)(f1 + 16 + nQ*4);
            }
        }
    }
    __syncthreads();

    // ---- stage A: vl[308][32] (BNS folded into wTi2) ----
    for (int ui = wv; ui < 20; ui += 4){
        int cls = ui/5, nt = ui%5;
        int pY = cls >> 1, pX = cls & 1;
        int s0 = nt*16 + nn;
        int s = s0 > 76 ? 76 : s0;
        int jr = s/7, jc = s%7;
        int ry = 2*jr + pY, rx = 2*jc + pX;
        int gY = y0-3+ry, gX = x0-3+rx;

        int tiy[4], tix[4], twk[4]; int tapN;
        if (pY == 0){
            int iA = ((gY-1)>>1) - uy0, iB = ((gY+1)>>1) - uy0;
            if (pX == 0){
                int jA = ((gX-1)>>1) - ux0, jB = ((gX+1)>>1) - ux0;
                tiy[0]=iA; tix[0]=jA; twk[0]=8;
                tiy[1]=iA; tix[1]=jB; twk[1]=6;
                tiy[2]=iB; tix[2]=jA; twk[2]=2;
                tiy[3]=iB; tix[3]=jB; twk[3]=0; tapN=4;
            } else {
                int j = (gX>>1) - ux0;
                tiy[0]=iA; tix[0]=j; twk[0]=7;
                tiy[1]=iB; tix[1]=j; twk[1]=1; tapN=2;
            }
        } else {
            int i2 = (gY>>1) - uy0;
            if (pX == 0){
                int jA = ((gX-1)>>1) - ux0, jB = ((gX+1)>>1) - ux0;
                tiy[0]=i2; tix[0]=jA; twk[0]=5;
                tiy[1]=i2; tix[1]=jB; twk[1]=3; tapN=2;
            } else {
                tiy[0]=i2; tix[0]=(gX>>1)-ux0; twk[0]=4; tapN=1;
            }
        }

        f32x4 acc0 = {0,0,0,0}, acc1 = {0,0,0,0};
        for (int t = 0; t < tapN; ++t){
            bf16x8 bfr = lds8(s_u + (tiy[t]*8 + tix[t])*36 + nQ*8);
            bf16x8 a0 = *(const bf16x8*)(wTi2 + twk[t]*1024 + nn*32 + nQ*8);
            bf16x8 a1 = *(const bf16x8*)(wTi2 + twk[t]*1024 + (16+nn)*32 + nQ*8);
            acc0 = MFMA_B16(a0, bfr, acc0, 0,0,0);
            acc1 = MFMA_B16(a1, bfr, acc1, 0,0,0);
        }
        if (s0 <= 76){
            int sidx = ry*14 + rx;
            u8 m = s_m[sidx];
            float r[8];
            #pragma unroll
            for (int g=0; g<2; ++g)
                #pragma unroll
                for (int e=0; e<4; ++e){
                    float a = g ? acc1[e] : acc0[e];
                    r[g*4+e] = m ? (a > 0.f ? a : 0.2f*a) : 0.f;
                }
            bf16x4 w0 = {f2bs(r[0]),f2bs(r[1]),f2bs(r[2]),f2bs(r[3])};
            bf16x4 w1 = {f2bs(r[4]),f2bs(r[5]),f2bs(r[6]),f2bs(r[7])};
            *(bf16x4*)(s_vl + sidx*36 + nQ*4) = w0;
            *(bf16x4*)(s_vl + sidx*36 + 16 + nQ*4) = w1;
        }
    }
    __syncthreads();

    // ---- stage B: v[240][32] = m ? conv(vl,l5) + fea1(prefetched) : 0 ----
    {
        bf16x8 wb0[9], wb1[9];
        #pragma unroll
        for (int k=0;k<9;++k){
            wb0[k] = *(const bf16x8*)(wTl5 + k*1024 + nn*32 + nQ*8);
            wb1[k] = *(const bf16x8*)(wTl5 + k*1024 + (16+nn)*32 + nQ*8);
        }
        #pragma unroll
        for (int u2 = 0; u2 < 4; ++u2){
            int nt = u2*4 + wv;
            if (nt >= 15) continue;
            int s0 = nt*16 + nn;
            int vy = s0/12, vx = s0%12;
            f32x4 acc0 = {0,0,0,0}, acc1 = {0,0,0,0};
            #pragma unroll
            for (int ky=0; ky<3; ++ky)
                #pragma unroll
                for (int kx=0; kx<3; ++kx){
                    const int k = ky*3+kx;
                    bf16x8 bfr = lds8(s_vl + ((vy+ky)*14 + vx+kx)*36 + nQ*8);
                    acc0 = MFMA_B16(wb0[k], bfr, acc0, 0,0,0);
                    acc1 = MFMA_B16(wb1[k], bfr, acc1, 0,0,0);
                }
            u8 m = s_m[(vy+1)*14 + vx+1];
            float r[8];
            #pragma unroll
            for (int g=0; g<2; ++g)
                #pragma unroll
                for (int e=0; e<4; ++e){
                    float a = g ? acc1[e] : acc0[e];
                    r[g*4+e] = m ? a + s2f(pf[u2][g][e]) : 0.f;
                }
            bf16x4 w0 = {f2bs(r[0]),f2bs(r[1]),f2bs(r[2]),f2bs(r[3])};
            bf16x4 w1 = {f2bs(r[4]),f2bs(r[5]),f2bs(r[6]),f2bs(r[7])};
            *(bf16x4*)(s_v + s0*36 + nQ*4) = w0;
            *(bf16x4*)(s_v + s0*36 + 16 + nQ*4) = w1;
        }
    }
    __syncthreads();

    // ---- stage C: t1[180][32] (BNS folded into wTr1a) ----
    {
        bf16x8 wc0[9], wc1[9];
        #pragma unroll
        for (int k=0;k<9;++k){
            wc0[k] = *(const bf16x8*)(wTr1a + k*1024 + nn*32 + nQ*8);
            wc1[k] = *(const bf16x8*)(wTr1a + k*1024 + (16+nn)*32 + nQ*8);
        }
        for (int nt = wv; nt < 12; nt += 4){
            int s0 = nt*16 + nn;
            int s = s0 > 179 ? 179 : s0;
            int qy = s/10, qx = s%10;
            f32x4 acc0 = {0,0,0,0}, acc1 = {0,0,0,0};
            #pragma unroll
            for (int ky=0; ky<3; ++ky)
                #pragma unroll
                for (int kx=0; kx<3; ++kx){
                    const int k = ky*3+kx;
                    bf16x8 bfr = lds8(s_v + ((qy+ky)*12 + qx+kx)*36 + nQ*8);
                    acc0 = MFMA_B16(wc0[k], bfr, acc0, 0,0,0);
                    acc1 = MFMA_B16(wc1[k], bfr, acc1, 0,0,0);
                }
            if (s0 <= 179){
                u8 m = s_m[(qy+2)*14 + qx+2];
                float r[8];
                #pragma unroll
                for (int g=0; g<2; ++g)
                    #pragma unroll
                    for (int e=0; e<4; ++e){
                        float a = g ? acc1[e] : acc0[e];
                        r[g*4+e] = m ? (a > 0.f ? a : 0.2f*a) : 0.f;
                    }
                bf16x4 w0 = {f2bs(r[0]),f2bs(r[1]),f2bs(r[2]),f2bs(r[3])};
                bf16x4 w1 = {f2bs(r[4]),f2bs(r[5]),f2bs(r[6]),f2bs(r[7])};
                *(bf16x4*)(s_t1 + s*36 + nQ*4) = w0;
                *(bf16x4*)(s_t1 + s*36 + 16 + nQ*4) = w1;
            }
        }
    }
    __syncthreads();

    // ---- stage D: out 16x8 via MFMA ----
    {
        float bb = r1_b2[0];
        #pragma unroll
        for (int u2 = 0; u2 < 2; ++u2){
            int nt = u2*4 + wv;
            int s0 = nt*16 + nn;
            int ty = s0 >> 3, tx = s0 & 7;
            f32x4 acc = {0,0,0,0};
            #pragma unroll
            for (int ky=0; ky<3; ++ky)
                #pragma unroll
                for (int kx=0; kx<3; ++kx){
                    const int k = ky*3+kx;
                    bf16x8 bfr = lds8(s_t1 + ((ty+ky)*10 + tx+kx)*36 + nQ*8);
                    bf16x8 aw = *(const bf16x8*)(wTr1b + k*512 + nn*32 + nQ*8);
                    acc = MFMA_B16(aw, bfr, acc, 0,0,0);
                }
            if (nQ == 0){
                u8 m = s_m[(ty+3)*14 + tx+3];
                float o = m ? acc[0] + bb : -99.f;
                out1[(size_t)n*HW1 + (y0+ty)*H1 + (x0+tx)] = o;
            }
        }
    }
}

// ---------------- launch ----------------

extern "C" void kernel_launch(void* const* d_in, const int* in_sizes, int n_in,
                              void* d_out, int out_size, void* d_ws, size_t ws_size,
                              hipStream_t stream)
{
    const float* x      = (const float*)d_in[0];
    const float* image  = (const float*)d_in[1];
    const float* masks  = (const float*)d_in[2];
    const float* roi    = (const float*)d_in[3];
    const float* w1a    = (const float*)d_in[4];
    const float* w1b    = (const float*)d_in[5];
    const float* w2a    = (const float*)d_in[6];
    const float* w2b    = (const float*)d_in[7];
    const float* w4a    = (const float*)d_in[8];
    const float* w4b    = (const float*)d_in[9];
    const float* inv4_w = (const float*)d_in[10];
    const float* l4_sub = (const float*)d_in[11];
    const float* inv2_w = (const float*)d_in[12];
    const float* l5_sub = (const float*)d_in[13];
    const float* r4_w1  = (const float*)d_in[14];
    const float* r4_w2  = (const float*)d_in[15];
    const float* r4_b2  = (const float*)d_in[16];
    const float* r1_w1  = (const float*)d_in[17];
    const float* r1_w2  = (const float*)d_in[18];
    const float* r1_b2  = (const float*)d_in[19];
    float* out = (float*)d_out;

    const int N = 8;
    const int H1 = 384, HW1 = 384*384;
    const int H2 = 192, HW2 = 192*192;
    const int H4 = 96,  HW4 = 96*96;

    char* wsp = (char*)d_ws;
    size_t off = 0;
    auto alloc = [&](size_t bytes) -> char* {
        char* p = wsp + off;
        off += (bytes + 255) & ~(size_t)255;
        return p;
    };
    bf16* FEA1 = (bf16*)alloc((size_t)N*32*HW1*2);  // interleaved [N][HW1][32]
    u8*   M1   = (u8*)alloc((size_t)N*HW1);
    u8*   M2   = (u8*)alloc((size_t)N*HW2);
    u8*   M4   = (u8*)alloc((size_t)N*HW4);
    bf16* FEA2 = (bf16*)alloc((size_t)N*32*HW2*2);
    bf16* XS   = (bf16*)alloc((size_t)N*64*HW4*2);
    bf16* GU   = (bf16*)alloc((size_t)N*32*HW2*2);  // g, then u
    bf16* HT   = (bf16*)alloc((size_t)N*64*HW4*2);  // h, then t_leaky
    short* WT   = (short*)alloc(6*9216*2);          // [w1bT, inv2T, l5T, r1aT, w2bT, w2aT]
    short* WT4  = (short*)alloc((size_t)129024*2);  // [inv4T, w4bT, l4sT, r4w1T, w4aT]
    short* WT1a = (short*)alloc(2048*2);
    short* WTh  = (short*)alloc(2*4608*2);          // [r1_w2 head, r4_w2 head]
    (void)ws_size; (void)in_sizes; (void)n_in; (void)out_size;

    short* wT1b  = WT;
    short* wTi2  = WT + 9216;
    short* wTl5  = WT + 2*9216;
    short* wTr1a = WT + 3*9216;
    short* wT2b  = WT + 4*9216;
    short* wT2a  = WT + 5*9216;
    short* wTi4  = WT4;
    short* wT4b  = WT4 + 36864;
    short* wTl4  = WT4 + 73728;
    short* wTr4a = WT4 + 92160;
    short* wT4a  = WT4 + 110592;
    short* wTr1b = WTh;
    short* wTr4b = WTh + 4608;

    dim3 blk(256);

    // masks + weight prep
    k_mask1<<<dim3((N*HW1 + 255)/256), blk, 0, stream>>>(roi, M1, N*HW1);
    k_down<<<dim3((HW2 + 255)/256, N), blk, 0, stream>>>(M1, M2, H1, H1, H2, H2);
    k_down<<<dim3((HW4 + 255)/256, N), blk, 0, stream>>>(M2, M4, H2, H2, H4, H4);
    k_wprep<<<dim3(36, 6), blk, 0, stream>>>(w1b, inv2_w, l5_sub, r1_w1, w2b, w2a, WT);
    k_wprep4<<<dim3(144, 5), blk, 0, stream>>>(inv4_w, w4b, l4_sub, r4_w1, w4a, WT4);
    k_wprep_misc<<<dim3(18, 3), blk, 0, stream>>>(w1a, r1_w2, r4_w2, WT1a, WTh);

    // front
    conv1ab3<<<dim3(1152, 1, N), blk, 0, stream>>>(image, masks, M1, WT1a, wT1b, (short*)FEA1);
    mconv_s2m<32,true><<<dim3(288, 1, N), blk, 0, stream>>>((const short*)FEA1, H1, wT2a, M2, (short*)GU, H2, 12);
    mconv_s1<32,32,0><<<dim3(144, 1, N), blk, 0, stream>>>((const short*)GU, H2, wT2b, M2, nullptr, (short*)FEA2, 12);
    mconv_s2m<64,false><<<dim3(72, 1, N), blk, 0, stream>>>((const short*)FEA2, H2, wT4a, M4, (short*)HT, H4, 6);
    mconv_s1<64,64,3><<<dim3(36, 1, N), blk, 0, stream>>>((const short*)HT, H4, wT4b, M4, x, (short*)XS, 6);

    // refine_OS4
    mconv_s1<64,32,1><<<dim3(36, 1, N), blk, 0, stream>>>((const short*)XS, H4, wTr4a, M4, nullptr, (short*)HT, 6);
    mconv_head32<<<dim3(36, 1, N), blk, 0, stream>>>((const short*)HT, H4, wTr4b, r4_b2, M4, out, 6);

    // layer4 fused (MFMA) -> u
    fk_l4c<<<dim3(144, 1, N), blk, 0, stream>>>((const short*)XS, (const short*)FEA2, M2,
                                                wTi4, wTl4, (short*)GU);

    // MFMA back end -> out1
    fk_back8<<<dim3(1152, 1, N), blk, 0, stream>>>((const short*)GU, (const short*)FEA1, M1,
                                                   wTi2, wTl5, wTr1a, wTr1b, r1_b2,
                                                   out + (size_t)N*HW4);
}

// Round 14
// 952.487 us; speedup vs baseline: 1.1481x; 1.0644x over previous
//
#include <hip/hip_runtime.h>
#include <hip/hip_bf16.h>

using bf16 = __hip_bfloat16;
typedef unsigned char u8;
typedef short bf16x8 __attribute__((ext_vector_type(8)));
typedef short bf16x4 __attribute__((ext_vector_type(4)));
typedef float f32x4 __attribute__((ext_vector_type(4)));

#define BNS 0.9999950000374997f   // folded into weights at prep time
#define MFMA_B16 __builtin_amdgcn_mfma_f32_16x16x32_bf16

__device__ __forceinline__ float b2f(bf16 v){ return __bfloat162float(v); }
__device__ __forceinline__ short f2bs(float v){ bf16 h = __float2bfloat16(v); return *reinterpret_cast<short*>(&h); }
__device__ __forceinline__ float s2f(short s){ union{unsigned u; float f;} x; x.u = ((unsigned)(unsigned short)s) << 16; return x.f; }

__device__ __forceinline__ bf16x8 lds8(const short* p){
    bf16x4 lo = *(const bf16x4*)(p);
    bf16x4 hi = *(const bf16x4*)(p + 4);
    bf16x8 r = {lo[0],lo[1],lo[2],lo[3],hi[0],hi[1],hi[2],hi[3]};
    return r;
}

// ---------------- mask kernels ----------------

__global__ __launch_bounds__(256) void k_mask1(const float* __restrict__ roi, u8* __restrict__ m1, int total){
    int i = blockIdx.x*256 + threadIdx.x;
    if (i < total) m1[i] = (roi[i] > 0.8f) ? 1 : 0;
}

__global__ __launch_bounds__(256) void k_down(const u8* __restrict__ mi, u8* __restrict__ mo,
                                              int IH, int IW, int OH, int OW){
    int p = blockIdx.x*256 + threadIdx.x;
    int n = blockIdx.y;
    if (p >= OH*OW) return;
    int oy = p / OW, ox = p - oy*OW;
    const u8* src = mi + (size_t)n*IH*IW;
    int v = 0;
    #pragma unroll
    for (int ky=0; ky<3; ky++){
        int iy = 2*oy + ky - 1;
        if ((unsigned)iy >= (unsigned)IH) continue;
        #pragma unroll
        for (int kx=0; kx<3; kx++){
            int ix = 2*ox + kx - 1;
            if ((unsigned)ix < (unsigned)IW) v |= src[iy*IW + ix];
        }
    }
    mo[(size_t)n*OH*OW + p] = (u8)v;
}

// ---- weight prep: 6 arrays [32][32][9] fp32 -> bf16 [9][32co][32ci]; BNS folded ----
__global__ __launch_bounds__(256) void k_wprep(const float* __restrict__ w1b,
                                               const float* __restrict__ i2,
                                               const float* __restrict__ l5,
                                               const float* __restrict__ r1a,
                                               const float* __restrict__ w2b,
                                               const float* __restrict__ w2a,
                                               short* __restrict__ dst){
    int a = blockIdx.y;
    const float* src = (a==0)? w1b : (a==1)? i2 : (a==2)? l5 : (a==3)? r1a : (a==4)? w2b : w2a;
    float sc = (a==2) ? 1.0f : BNS;
    int j = blockIdx.x*256 + threadIdx.x;
    if (j < 9216){
        int co = j/288, r = j%288, ci = r/9, k = r%9;
        dst[a*9216 + k*1024 + co*32 + ci] = f2bs(src[j]*sc);
    }
}

// ---- weight prep 64-wide; BNS folded except l4_sub ----
__global__ __launch_bounds__(256) void k_wprep4(const float* __restrict__ inv4,
                                                const float* __restrict__ w4b,
                                                const float* __restrict__ l4s,
                                                const float* __restrict__ r4w1,
                                                const float* __restrict__ w4a,
                                                short* __restrict__ dst)
{
    int a = blockIdx.y;
    int j = blockIdx.x*256 + threadIdx.x;
    if (a < 2){
        if (j < 36864){
            int co = j/576, r = j%576, ci = r/9, k = r%9;
            const float* s = a ? w4b : inv4;
            dst[a*36864 + k*4096 + co*64 + ci] = f2bs(s[j]*BNS);
        }
    } else if (a < 4){
        if (j < 18432){
            int co = j/576, r = j%576, ci = r/9, k = r%9;
            const float* s = (a==2) ? l4s : r4w1;
            float sc = (a==2) ? 1.0f : BNS;
            dst[73728 + (a-2)*18432 + k*2048 + co*64 + ci] = f2bs(s[j]*sc);
        }
    } else {
        if (j < 18432){
            int co = j/288, r = j%288, ci = r/9, k = r%9;
            dst[110592 + k*2048 + co*32 + ci] = f2bs(w4a[j]*BNS);
        }
    }
}

// ---- misc prep ----
__global__ __launch_bounds__(256) void k_wprep_misc(const float* __restrict__ w1a,
                                                    const float* __restrict__ r1w2,
                                                    const float* __restrict__ r4w2,
                                                    short* __restrict__ d1a,
                                                    short* __restrict__ dh){
    int a = blockIdx.y;
    int j = blockIdx.x*256 + threadIdx.x;
    if (a == 0){
        if (j < 2048){
            int h = j >> 10, r = j & 1023, co = r >> 5, kq = r & 31;
            int q = h*32 + kq;
            d1a[j] = (q < 36) ? f2bs(w1a[co*36 + q]*BNS) : 0;
        }
    } else {
        if (j < 4608){
            int k = j/512, r = j%512, co = r/32, ci = r%32;
            const float* s = (a==1) ? r1w2 : r4w2;
            dh[(a-1)*4608 + j] = (co == 0) ? f2bs(s[ci*9 + k]) : 0;
        }
    }
}

// ---------------- generic MFMA stride-1 conv; TH = tile height (16 or 8) --------------
template<int CIN, int COUT, int EPI, int TH>
__global__ __launch_bounds__(256) void mconv_s1(const short* __restrict__ in, int H,
                                                const short* __restrict__ wT,
                                                const u8* __restrict__ mask,
                                                const float* __restrict__ res32,
                                                short* __restrict__ out, int tilesX)
{
    const int HW = H*H;
    const int HV = CIN/32, G = COUT/16;
    const int SR = TH + 2;            // staged rows
    const int SITES = SR*18;
    int tY = blockIdx.x / tilesX, tX = blockIdx.x % tilesX, n = blockIdx.z;
    int y0 = tY*TH, x0 = tX*16;

    __shared__ __align__(16) short s_in[HV*SITES*36];
    __shared__ u8 s_m[TH*16];

    int tid = threadIdx.x;
    const short* inN = in + (size_t)n*CIN*HW;
    for (int i = tid; i < CIN*SITES; i += 256){
        int c = i/SITES, r = i%SITES;
        int ry = r/18, rx = r%18;
        int gy = y0-1+ry, gx = x0-1+rx;
        short v = 0;
        if ((unsigned)gy < (unsigned)H && (unsigned)gx < (unsigned)H)
            v = inN[(size_t)c*HW + gy*H + gx];
        s_in[(c>>5)*(SITES*36) + r*36 + (c&31)] = v;
    }
    for (int i = tid; i < TH*16; i += 256){
        int ty = i>>4, tx = i&15;
        s_m[i] = mask[(size_t)n*HW + (y0+ty)*H + x0+tx];
    }
    __syncthreads();

    int wv = tid >> 6, lane = tid & 63;
    int nQ = lane >> 4, nn = lane & 15;

    bf16x8 wa0[9], wa1[9];
    if constexpr (CIN == 32 && COUT == 32){
        #pragma unroll
        for (int k=0;k<9;++k){
            wa0[k] = *(const bf16x8*)(wT + k*1024 + nn*32 + nQ*8);
            wa1[k] = *(const bf16x8*)(wT + k*1024 + (16+nn)*32 + nQ*8);
        }
    }

    #pragma unroll
    for (int u2 = 0; u2 < TH/4; ++u2){
        int nt = u2*4 + wv;
        int ty = nt, tx = nn;
        f32x4 acc[G];
        #pragma unroll
        for (int g=0;g<G;++g) acc[g] = (f32x4){0,0,0,0};
        #pragma unroll
        for (int ky=0; ky<3; ++ky)
            #pragma unroll
            for (int kx=0; kx<3; ++kx){
                const int k = ky*3+kx;
                #pragma unroll
                for (int h=0; h<HV; ++h){
                    bf16x8 bfr = lds8(s_in + h*(SITES*36) + ((ty+ky)*18 + tx+kx)*36 + nQ*8);
                    #pragma unroll
                    for (int g=0; g<G; ++g){
                        bf16x8 a;
                        if constexpr (CIN == 32 && COUT == 32) a = g ? wa1[k] : wa0[k];
                        else a = *(const bf16x8*)(wT + k*COUT*CIN + (g*16+nn)*CIN + h*32 + nQ*8);
                        acc[g] = MFMA_B16(a, bfr, acc[g], 0,0,0);
                    }
                }
            }
        int p = (y0+ty)*H + x0+tx;
        u8 m = s_m[nt*16 + nn];
        short* op = out + (size_t)n*COUT*HW + p;
        #pragma unroll
        for (int g=0; g<G; ++g)
            #pragma unroll
            for (int e=0; e<4; ++e){
                int co = g*16 + nQ*4 + e;
                float a = acc[g][e], o;
                if      (EPI == 0) o = m ? fmaxf(a,0.f) : 0.f;
                else if (EPI == 1) o = m ? (a > 0.f ? a : 0.2f*a) : 0.f;
                else o = m ? fmaxf(a,0.f) + res32[((size_t)(n>>2)*COUT + co)*(size_t)HW + p] : 0.f;
                op[(size_t)co*HW] = f2bs(o);
            }
    }
}

// ---------------- MFMA COUT=1 head; TH-tiled ----------------
template<int TH>
__global__ __launch_bounds__(256) void mconv_head32(const short* __restrict__ in, int H,
                                                    const short* __restrict__ wTh,  // [9][16][32]
                                                    const float* __restrict__ bias,
                                                    const u8* __restrict__ mask,
                                                    float* __restrict__ out, int tilesX)
{
    const int HW = H*H;
    const int SR = TH + 2, SITES = SR*18;
    int tY = blockIdx.x / tilesX, tX = blockIdx.x % tilesX, n = blockIdx.z;
    int y0 = tY*TH, x0 = tX*16;

    __shared__ __align__(16) short s_in[SITES*36];
    __shared__ u8 s_m[TH*16];

    int tid = threadIdx.x;
    const short* inN = in + (size_t)n*32*HW;
    for (int i = tid; i < 32*SITES; i += 256){
        int c = i/SITES, r = i%SITES;
        int ry = r/18, rx = r%18;
        int gy = y0-1+ry, gx = x0-1+rx;
        short v = 0;
        if ((unsigned)gy < (unsigned)H && (unsigned)gx < (unsigned)H)
            v = inN[(size_t)c*HW + gy*H + gx];
        s_in[r*36 + c] = v;
    }
    for (int i = tid; i < TH*16; i += 256){
        int ty = i>>4, tx = i&15;
        s_m[i] = mask[(size_t)n*HW + (y0+ty)*H + x0+tx];
    }
    __syncthreads();

    int wv = tid >> 6, lane = tid & 63;
    int nQ = lane >> 4, nn = lane & 15;
    float bb = bias[0];

    for (int nt = wv; nt < TH; nt += 4){
        int ty = nt, tx = nn;
        f32x4 acc = {0,0,0,0};
        #pragma unroll
        for (int ky=0; ky<3; ++ky)
            #pragma unroll
            for (int kx=0; kx<3; ++kx){
                const int k = ky*3+kx;
                bf16x8 bfr = lds8(s_in + ((ty+ky)*18 + tx+kx)*36 + nQ*8);
                bf16x8 aw = *(const bf16x8*)(wTh + k*512 + nn*32 + nQ*8);
                acc = MFMA_B16(aw, bfr, acc, 0,0,0);
            }
        if (nQ == 0){
            u8 m = s_m[nt*16 + nn];
            int p = (y0+ty)*H + x0+tx;
            out[(size_t)n*HW + p] = m ? acc[0] + bb : -99.f;
        }
    }
}

// ---------------- MFMA stride-2 conv: tile 8x16, CIN=32; IL = input interleaved --------
template<int COUT, bool IL>
__global__ __launch_bounds__(256) void mconv_s2m(const short* __restrict__ in, int IH,
                                                 const short* __restrict__ wT,   // [9][COUT][32]
                                                 const u8* __restrict__ mask,
                                                 short* __restrict__ out, int OH, int tilesX)
{
    const int IHW = IH*IH, OHW = OH*OH, G = COUT/16;
    int tY = blockIdx.x / tilesX, tX = blockIdx.x % tilesX, n = blockIdx.z;
    int y0 = tY*8, x0 = tX*16;

    __shared__ __align__(16) short s_in[561*36];
    __shared__ u8 s_m[128];

    int tid = threadIdx.x;
    const short* inN = in + (size_t)n*32*IHW;
    for (int i = tid; i < 32*561; i += 256){
        int c, r;
        if constexpr (IL){ c = i & 31; r = i >> 5; }
        else             { c = i/561;  r = i%561; }
        int ry = r/33, rx = r%33;
        int gy = 2*y0-1+ry, gx = 2*x0-1+rx;
        short v = 0;
        if ((unsigned)gy < (unsigned)IH && (unsigned)gx < (unsigned)IH){
            if constexpr (IL) v = inN[((size_t)gy*IH + gx)*32 + c];
            else              v = inN[(size_t)c*IHW + (size_t)gy*IH + gx];
        }
        s_in[r*36 + c] = v;
    }
    for (int i = tid; i < 128; i += 256){
        int ty = i>>4, tx = i&15;
        s_m[i] = mask[(size_t)n*OHW + (y0+ty)*OH + x0+tx];
    }
    __syncthreads();

    int wv = tid >> 6, lane = tid & 63;
    int nQ = lane >> 4, nn = lane & 15;

    for (int nt = wv; nt < 8; nt += 4){
        int ty = nt, tx = nn;
        f32x4 acc[G];
        #pragma unroll
        for (int g=0;g<G;++g) acc[g] = (f32x4){0,0,0,0};
        #pragma unroll
        for (int ky=0; ky<3; ++ky)
            #pragma unroll
            for (int kx=0; kx<3; ++kx){
                const int k = ky*3+kx;
                bf16x8 bfr = lds8(s_in + ((2*ty+ky)*33 + 2*tx+kx)*36 + nQ*8);
                #pragma unroll
                for (int g=0; g<G; ++g){
                    bf16x8 a = *(const bf16x8*)(wT + k*COUT*32 + (g*16+nn)*32 + nQ*8);
                    acc[g] = MFMA_B16(a, bfr, acc[g], 0,0,0);
                }
            }
        int p = (y0+ty)*OH + x0+tx;
        u8 m = s_m[nt*16 + nn];
        short* op = out + (size_t)n*COUT*OHW + p;
        #pragma unroll
        for (int g=0; g<G; ++g)
            #pragma unroll
            for (int e=0; e<4; ++e){
                int co = g*16 + nQ*4 + e;
                float o = m ? fmaxf(acc[g][e],0.f) : 0.f;
                op[(size_t)co*OHW] = f2bs(o);
            }
    }
}

// ---------------- conv1ab v5: im2col MFMA f-stage + MFMA stage-2; fea1 interleaved ----
__global__ __launch_bounds__(256) void conv1ab3(const float* __restrict__ image,
                                                const float* __restrict__ masks,
                                                const u8*  __restrict__ M1,
                                                const short* __restrict__ wT1a,   // [2][32co][32K]
                                                const short* __restrict__ wT1b,   // [9][32co][32ci]
                                                short* __restrict__ fea1)         // [N][HW][32]
{
    const int H = 384; const int HW = H*H;
    int tY = blockIdx.x / 48, tX = blockIdx.x % 48, n = blockIdx.z;
    int y0 = tY*16, x0 = tX*8;

    __shared__ float s_inp[4][240];
    __shared__ u8    s_m[240];
    __shared__ __align__(16) short s_ic[180*72];
    short* s_f = s_ic;

    int tid = threadIdx.x;
    for (int i = tid; i < 240; i += 256){
        int ly = i/12, lxx = i%12;
        int gy = y0-2+ly, gx = x0-2+lxx;
        bool inb = ((unsigned)gy < 384u) && ((unsigned)gx < 384u);
        u8 mv = inb ? M1[(size_t)n*HW + gy*H + gx] : 0;
        s_m[i] = mv;
        float mm = (float)mv;
        int p = gy*H + gx;
        #pragma unroll
        for (int c = 0; c < 4; ++c){
            float v = 0.f;
            if (inb) v = (c < 3) ? image[((size_t)(n>>2)*3 + c)*HW + p]
                                 : masks[(size_t)n*HW + p];
            s_inp[c][i] = v*mm;
        }
    }
    __syncthreads();

    for (int i = tid; i < 180*64; i += 256){
        int site = i >> 6, q = i & 63;
        short v = 0;
        if (q < 36){
            int ci = q/9, k = q - ci*9, ky = k/3, kx = k - ky*3;
            int fy = site/10, fx = site - fy*10;
            v = f2bs(s_inp[ci][(fy+ky)*12 + fx+kx]);
        }
        s_ic[site*72 + q] = v;
    }
    __syncthreads();

    int wv = tid >> 6, lane = tid & 63;
    int nQ = lane >> 4, nn = lane & 15;

    f32x4 fr[3][2];
    {
        bf16x8 fa0[2], fa1[2];
        #pragma unroll
        for (int h=0;h<2;++h){
            fa0[h] = *(const bf16x8*)(wT1a + h*1024 + nn*32 + nQ*8);
            fa1[h] = *(const bf16x8*)(wT1a + h*1024 + (16+nn)*32 + nQ*8);
        }
        #pragma unroll
        for (int u=0; u<3; ++u){
            int nt = u*4 + wv;
            int s0 = nt*16 + nn;
            int s = s0 > 179 ? 179 : s0;
            f32x4 a0 = {0,0,0,0}, a1 = {0,0,0,0};
            #pragma unroll
            for (int h=0;h<2;++h){
                bf16x8 bfr = lds8(s_ic + s*72 + h*32 + nQ*8);
                a0 = MFMA_B16(fa0[h], bfr, a0, 0,0,0);
                a1 = MFMA_B16(fa1[h], bfr, a1, 0,0,0);
            }
            fr[u][0] = a0; fr[u][1] = a1;
        }
    }
    __syncthreads();

    #pragma unroll
    for (int u=0; u<3; ++u){
        int nt = u*4 + wv;
        int s0 = nt*16 + nn;
        if (s0 <= 179){
            int fy = s0/10, fx = s0 - fy*10;
            u8 m = s_m[(fy+1)*12 + fx+1];
            #pragma unroll
            for (int g=0; g<2; ++g){
                float r[4];
                #pragma unroll
                for (int e=0; e<4; ++e){
                    float a = fr[u][g][e];
                    r[e] = m ? fmaxf(a,0.f) : 0.f;
                }
                bf16x4 w4 = {f2bs(r[0]),f2bs(r[1]),f2bs(r[2]),f2bs(r[3])};
                *(bf16x4*)(s_f + s0*36 + g*16 + nQ*4) = w4;
            }
        }
    }
    __syncthreads();

    bf16x8 wa0[9], wa1[9];
    #pragma unroll
    for (int k=0;k<9;++k){
        wa0[k] = *(const bf16x8*)(wT1b + k*1024 + nn*32 + nQ*8);
        wa1[k] = *(const bf16x8*)(wT1b + k*1024 + (16+nn)*32 + nQ*8);
    }
    for (int nt = wv; nt < 8; nt += 4){
        int s0 = nt*16 + nn;
        int ty = s0 >> 3, tx = s0 & 7;
        f32x4 acc0 = {0,0,0,0}, acc1 = {0,0,0,0};
        #pragma unroll
        for (int ky=0; ky<3; ++ky)
            #pragma unroll
            for (int kx=0; kx<3; ++kx){
                const int k = ky*3+kx;
                bf16x8 bfr = lds8(s_f + ((ty+ky)*10 + tx+kx)*36 + nQ*8);
                acc0 = MFMA_B16(wa0[k], bfr, acc0, 0,0,0);
                acc1 = MFMA_B16(wa1[k], bfr, acc1, 0,0,0);
            }
        u8 m = s_m[(ty+2)*12 + tx+2];
        short* fp = fea1 + ((size_t)n*HW + (size_t)(y0+ty)*H + (x0+tx))*32;
        #pragma unroll
        for (int g=0; g<2; ++g){
            float r[4];
            #pragma unroll
            for (int e=0; e<4; ++e){
                float a = g ? acc1[e] : acc0[e];
                r[e] = m ? fmaxf(a,0.f) : 0.f;
            }
            bf16x4 w4 = {f2bs(r[0]),f2bs(r[1]),f2bs(r[2]),f2bs(r[3])};
            *(bf16x4*)(fp + g*16 + nQ*4) = w4;
        }
    }
}

// ---------------- MFMA layer4 (round-10 staging + fea2 prefetch) ----------------
__global__ __launch_bounds__(256) void fk_l4c(const short* __restrict__ xs,
                                              const short* __restrict__ fea2,
                                              const u8*  __restrict__ M2,
                                              const short* __restrict__ wTi4,
                                              const short* __restrict__ wTl4,
                                              short* __restrict__ u_out)
{
    const int H2 = 192, HW2 = H2*H2, H4 = 96, HW4 = H4*H4;
    int tY = blockIdx.x / 12, tX = blockIdx.x % 12, n = blockIdx.z;
    int y0 = tY*16, x0 = tX*16;
    int uy0 = (y0>>1) - 1, ux0 = (x0>>1) - 1;

    __shared__ __align__(16) short s_xs[2*100*36];
    __shared__ __align__(16) short s_ul[2*324*36];
    __shared__ u8 s_m[324];

    int tid = threadIdx.x;
    const short* xN = xs + (size_t)n*64*HW4;
    for (int i = tid; i < 64*100; i += 256){
        int c = i/100, r = i%100; int ly = r/10, lxx = r%10;
        int gy = uy0+ly, gx = ux0+lxx;
        short v = 0;
        if ((unsigned)gy < 96u && (unsigned)gx < 96u) v = xN[(size_t)c*HW4 + gy*H4 + gx];
        s_xs[(c>>5)*3600 + r*36 + (c&31)] = v;
    }
    for (int i = tid; i < 324; i += 256){
        int ry = i/18, rx = i%18; int gy = y0-1+ry, gx = x0-1+rx;
        s_m[i] = ((unsigned)gy < 192u && (unsigned)gx < 192u) ? M2[(size_t)n*HW2 + gy*H2 + gx] : 0;
    }

    int wv = tid >> 6, lane = tid & 63;
    int nQ = lane >> 4, nn = lane & 15;

    short pf2[4][8];
    {
        const short* f2N = fea2 + (size_t)n*32*HW2;
        #pragma unroll
        for (int u2=0; u2<4; ++u2){
            int nt = u2*4 + wv;
            int p = (y0+nt)*H2 + x0+nn;
            #pragma unroll
            for (int g=0; g<2; ++g)
                #pragma unroll
                for (int e=0; e<4; ++e){
                    int co = g*16 + nQ*4 + e;
                    pf2[u2][g*4+e] = f2N[(size_t)co*HW2 + p];
                }
        }
    }
    __syncthreads();

    for (int ui = wv; ui < 24; ui += 4){
        int cls = ui/6, nt = ui%6;
        int pY = cls >> 1, pX = cls & 1;
        int s0 = nt*16 + nn;
        int s = s0 > 80 ? 80 : s0;
        int jr = s/9, jc = s%9;
        int ry = 2*jr + pY, rx = 2*jc + pX;
        int gY = y0-1+ry, gX = x0-1+rx;

        int tiy[4], tix[4], twk[4]; int tapN;
        if (pY == 0){
            int iA = ((gY-1)>>1) - uy0, iB = ((gY+1)>>1) - uy0;
            if (pX == 0){
                int jA = ((gX-1)>>1) - ux0, jB = ((gX+1)>>1) - ux0;
                tiy[0]=iA; tix[0]=jA; twk[0]=8;
                tiy[1]=iA; tix[1]=jB; twk[1]=6;
                tiy[2]=iB; tix[2]=jA; twk[2]=2;
                tiy[3]=iB; tix[3]=jB; twk[3]=0; tapN=4;
            } else {
                int j = (gX>>1) - ux0;
                tiy[0]=iA; tix[0]=j; twk[0]=7;
                tiy[1]=iB; tix[1]=j; twk[1]=1; tapN=2;
            }
        } else {
            int i2 = (gY>>1) - uy0;
            if (pX == 0){
                int jA = ((gX-1)>>1) - ux0, jB = ((gX+1)>>1) - ux0;
                tiy[0]=i2; tix[0]=jA; twk[0]=5;
                tiy[1]=i2; tix[1]=jB; twk[1]=3; tapN=2;
            } else {
                tiy[0]=i2; tix[0]=(gX>>1)-ux0; twk[0]=4; tapN=1;
            }
        }

        f32x4 acc[4];
        #pragma unroll
        for (int g=0; g<4; ++g) acc[g] = (f32x4){0,0,0,0};
        for (int t = 0; t < tapN; ++t){
            int off = (tiy[t]*10 + tix[t])*36 + nQ*8;
            bf16x8 xlo = lds8(s_xs + off);
            bf16x8 xhi = lds8(s_xs + 3600 + off);
            const short* wk = wTi4 + twk[t]*4096;
            #pragma unroll
            for (int g=0; g<4; ++g){
                bf16x8 alo = *(const bf16x8*)(wk + (g*16+nn)*64 + nQ*8);
                bf16x8 ahi = *(const bf16x8*)(wk + (g*16+nn)*64 + 32 + nQ*8);
                acc[g] = MFMA_B16(alo, xlo, acc[g], 0,0,0);
                acc[g] = MFMA_B16(ahi, xhi, acc[g], 0,0,0);
            }
        }
        if (s0 <= 80){
            int sidx = ry*18 + rx;
            u8 m = s_m[sidx];
            #pragma unroll
            for (int g=0; g<4; ++g){
                float r[4];
                #pragma unroll
                for (int e=0; e<4; ++e){
                    float a = acc[g][e];
                    r[e] = m ? (a > 0.f ? a : 0.2f*a) : 0.f;
                }
                bf16x4 w4 = {f2bs(r[0]),f2bs(r[1]),f2bs(r[2]),f2bs(r[3])};
                *(bf16x4*)(s_ul + (g>>1)*11664 + sidx*36 + (g&1)*16 + nQ*4) = w4;
            }
        }
    }
    __syncthreads();

    #pragma unroll
    for (int u2 = 0; u2 < 4; ++u2){
        int nt = u2*4 + wv;
        int ty = nt, tx = nn;
        f32x4 acc0 = {0,0,0,0}, acc1 = {0,0,0,0};
        #pragma unroll
        for (int ky=0; ky<3; ++ky)
            #pragma unroll
            for (int kx=0; kx<3; ++kx){
                int k = ky*3+kx;
                int off = ((ty+ky)*18 + tx+kx)*36 + nQ*8;
                bf16x8 vlo = lds8(s_ul + off);
                bf16x8 vhi = lds8(s_ul + 11664 + off);
                const short* wk = wTl4 + k*2048;
                bf16x8 a0lo = *(const bf16x8*)(wk + nn*64 + nQ*8);
                bf16x8 a0hi = *(const bf16x8*)(wk + nn*64 + 32 + nQ*8);
                bf16x8 a1lo = *(const bf16x8*)(wk + (16+nn)*64 + nQ*8);
                bf16x8 a1hi = *(const bf16x8*)(wk + (16+nn)*64 + 32 + nQ*8);
                acc0 = MFMA_B16(a0lo, vlo, acc0, 0,0,0);
                acc0 = MFMA_B16(a0hi, vhi, acc0, 0,0,0);
                acc1 = MFMA_B16(a1lo, vlo, acc1, 0,0,0);
                acc1 = MFMA_B16(a1hi, vhi, acc1, 0,0,0);
            }
        int gy = y0+ty, gx = x0+tx;
        int p = gy*H2 + gx;
        u8 m = s_m[(ty+1)*18 + tx+1];
        short* up = u_out + (size_t)n*32*HW2 + p;
        #pragma unroll
        for (int g=0; g<2; ++g)
            #pragma unroll
            for (int e=0; e<4; ++e){
                int co = g*16 + nQ*4 + e;
                float a = g ? acc1[e] : acc0[e];
                float o = m ? a + s2f(pf2[u2][g*4+e]) : 0.f;
                up[(size_t)co*HW2] = f2bs(o);
            }
    }
}

// ---------------- MFMA back end v8 (unchanged from passing round 13) ----------------
__global__ __launch_bounds__(256) void fk_back8(const short* __restrict__ u,
                                                const short* __restrict__ fea1,   // [N][HW1][32]
                                                const u8*  __restrict__ M1,
                                                const short* __restrict__ wTi2,
                                                const short* __restrict__ wTl5,
                                                const short* __restrict__ wTr1a,
                                                const short* __restrict__ wTr1b,  // [9][16][32]
                                                const float* __restrict__ r1_b2,
                                                float* __restrict__ out1)
{
    const int H1 = 384, HW1 = H1*H1, H2 = 192, HW2 = H2*H2;
    int tY = blockIdx.x / 48, tX = blockIdx.x % 48, n = blockIdx.z;
    int y0 = tY*16, x0 = tX*8;
    int uy0 = (y0>>1) - 2, ux0 = (x0>>1) - 2;

    __shared__ __align__(16) short sP0[308*36];
    __shared__ __align__(16) short sP1[240*36];
    __shared__ u8 s_m[308];
    short* s_u  = sP1;
    short* s_vl = sP0;
    short* s_v  = sP1;
    short* s_t1 = sP0;

    int tid = threadIdx.x;
    const short* uN = u + (size_t)n*32*HW2;
    {
        int cc = tid >> 3, r0 = tid & 7;
        const short* src = uN + (size_t)cc*HW2;
        for (int r = r0; r < 96; r += 8){
            int ly = r >> 3, lxx = r & 7;
            int gy = uy0+ly, gx = ux0+lxx;
            short v = 0;
            if ((unsigned)gy < 192u && (unsigned)gx < 192u) v = src[(size_t)gy*H2 + gx];
            s_u[r*36 + cc] = v;
        }
    }
    for (int i = tid; i < 308; i += 256){
        int ry = i/14, rx = i%14; int gy = y0-3+ry, gx = x0-3+rx;
        s_m[i] = ((unsigned)gy < 384u && (unsigned)gx < 384u) ? M1[(size_t)n*HW1 + gy*H1 + gx] : 0;
    }

    int wv = tid >> 6, lane = tid & 63;
    int nQ = lane >> 4, nn = lane & 15;

    bf16x4 pf[4][2];
    {
        #pragma unroll
        for (int u2=0; u2<4; ++u2){
            int nt = u2*4 + wv;
            if (nt < 15){
                int s0 = nt*16 + nn;
                int vy = s0/12, vx = s0%12;
                int gY = y0-2+vy, gX = x0-2+vx;
                int gyc = gY < 0 ? 0 : (gY > 383 ? 383 : gY);
                int gxc = gX < 0 ? 0 : (gX > 383 ? 383 : gX);
                const short* f1 = fea1 + ((size_t)n*HW1 + (size_t)gyc*H1 + gxc)*32;
                pf[u2][0] = *(const bf16x4*)(f1 + nQ*4);
                pf[u2][1] = *(const bf16x4*)(f1 + 16 + nQ*4);
            }
        }
    }
    __syncthreads();

    // ---- stage A ----
    for (int ui = wv; ui < 20; ui += 4){
        int cls = ui/5, nt = ui%5;
        int pY = cls >> 1, pX = cls & 1;
        int s0 = nt*16 + nn;
        int s = s0 > 76 ? 76 : s0;
        int jr = s/7, jc = s%7;
        int ry = 2*jr + pY, rx = 2*jc + pX;
        int gY = y0-3+ry, gX = x0-3+rx;

        int tiy[4], tix[4], twk[4]; int tapN;
        if (pY == 0){
            int iA = ((gY-1)>>1) - uy0, iB = ((gY+1)>>1) - uy0;
            if (pX == 0){
                int jA = ((gX-1)>>1) - ux0, jB = ((gX+1)>>1) - ux0;
                tiy[0]=iA; tix[0]=jA; twk[0]=8;
                tiy[1]=iA; tix[1]=jB; twk[1]=6;
                tiy[2]=iB; tix[2]=jA; twk[2]=2;
                tiy[3]=iB; tix[3]=jB; twk[3]=0; tapN=4;
            } else {
                int j = (gX>>1) - ux0;
                tiy[0]=iA; tix[0]=j; twk[0]=7;
                tiy[1]=iB; tix[1]=j; twk[1]=1; tapN=2;
            }
        } else {
            int i2 = (gY>>1) - uy0;
            if (pX == 0){
                int jA = ((gX-1)>>1) - ux0, jB = ((gX+1)>>1) - ux0;
                tiy[0]=i2; tix[0]=jA; twk[0]=5;
                tiy[1]=i2; tix[1]=jB; twk[1]=3; tapN=2;
            } else {
                tiy[0]=i2; tix[0]=(gX>>1)-ux0; twk[0]=4; tapN=1;
            }
        }

        f32x4 acc0 = {0,0,0,0}, acc1 = {0,0,0,0};
        for (int t = 0; t < tapN; ++t){
            bf16x8 bfr = lds8(s_u + (tiy[t]*8 + tix[t])*36 + nQ*8);
            bf16x8 a0 = *(const bf16x8*)(wTi2 + twk[t]*1024 + nn*32 + nQ*8);
            bf16x8 a1 = *(const bf16x8*)(wTi2 + twk[t]*1024 + (16+nn)*32 + nQ*8);
            acc0 = MFMA_B16(a0, bfr, acc0, 0,0,0);
            acc1 = MFMA_B16(a1, bfr, acc1, 0,0,0);
        }
        if (s0 <= 76){
            int sidx = ry*14 + rx;
            u8 m = s_m[sidx];
            float r[8];
            #pragma unroll
            for (int g=0; g<2; ++g)
                #pragma unroll
                for (int e=0; e<4; ++e){
                    float a = g ? acc1[e] : acc0[e];
                    r[g*4+e] = m ? (a > 0.f ? a : 0.2f*a) : 0.f;
                }
            bf16x4 w0 = {f2bs(r[0]),f2bs(r[1]),f2bs(r[2]),f2bs(r[3])};
            bf16x4 w1 = {f2bs(r[4]),f2bs(r[5]),f2bs(r[6]),f2bs(r[7])};
            *(bf16x4*)(s_vl + sidx*36 + nQ*4) = w0;
            *(bf16x4*)(s_vl + sidx*36 + 16 + nQ*4) = w1;
        }
    }
    __syncthreads();

    // ---- stage B ----
    {
        bf16x8 wb0[9], wb1[9];
        #pragma unroll
        for (int k=0;k<9;++k){
            wb0[k] = *(const bf16x8*)(wTl5 + k*1024 + nn*32 + nQ*8);
            wb1[k] = *(const bf16x8*)(wTl5 + k*1024 + (16+nn)*32 + nQ*8);
        }
        #pragma unroll
        for (int u2 = 0; u2 < 4; ++u2){
            int nt = u2*4 + wv;
            if (nt >= 15) continue;
            int s0 = nt*16 + nn;
            int vy = s0/12, vx = s0%12;
            f32x4 acc0 = {0,0,0,0}, acc1 = {0,0,0,0};
            #pragma unroll
            for (int ky=0; ky<3; ++ky)
                #pragma unroll
                for (int kx=0; kx<3; ++kx){
                    const int k = ky*3+kx;
                    bf16x8 bfr = lds8(s_vl + ((vy+ky)*14 + vx+kx)*36 + nQ*8);
                    acc0 = MFMA_B16(wb0[k], bfr, acc0, 0,0,0);
                    acc1 = MFMA_B16(wb1[k], bfr, acc1, 0,0,0);
                }
            u8 m = s_m[(vy+1)*14 + vx+1];
            float r[8];
            #pragma unroll
            for (int g=0; g<2; ++g)
                #pragma unroll
                for (int e=0; e<4; ++e){
                    float a = g ? acc1[e] : acc0[e];
                    r[g*4+e] = m ? a + s2f(pf[u2][g][e]) : 0.f;
                }
            bf16x4 w0 = {f2bs(r[0]),f2bs(r[1]),f2bs(r[2]),f2bs(r[3])};
            bf16x4 w1 = {f2bs(r[4]),f2bs(r[5]),f2bs(r[6]),f2bs(r[7])};
            *(bf16x4*)(s_v + s0*36 + nQ*4) = w0;
            *(bf16x4*)(s_v + s0*36 + 16 + nQ*4) = w1;
        }
    }
    __syncthreads();

    // ---- stage C ----
    {
        bf16x8 wc0[9], wc1[9];
        #pragma unroll
        for (int k=0;k<9;++k){
            wc0[k] = *(const bf16x8*)(wTr1a + k*1024 + nn*32 + nQ*8);
            wc1[k] = *(const bf16x8*)(wTr1a + k*1024 + (16+nn)*32 + nQ*8);
        }
        for (int nt = wv; nt < 12; nt += 4){
            int s0 = nt*16 + nn;
            int s = s0 > 179 ? 179 : s0;
            int qy = s/10, qx = s%10;
            f32x4 acc0 = {0,0,0,0}, acc1 = {0,0,0,0};
            #pragma unroll
            for (int ky=0; ky<3; ++ky)
                #pragma unroll
                for (int kx=0; kx<3; ++kx){
                    const int k = ky*3+kx;
                    bf16x8 bfr = lds8(s_v + ((qy+ky)*12 + qx+kx)*36 + nQ*8);
                    acc0 = MFMA_B16(wc0[k], bfr, acc0, 0,0,0);
                    acc1 = MFMA_B16(wc1[k], bfr, acc1, 0,0,0);
                }
            if (s0 <= 179){
                u8 m = s_m[(qy+2)*14 + qx+2];
                float r[8];
                #pragma unroll
                for (int g=0; g<2; ++g)
                    #pragma unroll
                    for (int e=0; e<4; ++e){
                        float a = g ? acc1[e] : acc0[e];
                        r[g*4+e] = m ? (a > 0.f ? a : 0.2f*a) : 0.f;
                    }
                bf16x4 w0 = {f2bs(r[0]),f2bs(r[1]),f2bs(r[2]),f2bs(r[3])};
                bf16x4 w1 = {f2bs(r[4]),f2bs(r[5]),f2bs(r[6]),f2bs(r[7])};
                *(bf16x4*)(s_t1 + s*36 + nQ*4) = w0;
                *(bf16x4*)(s_t1 + s*36 + 16 + nQ*4) = w1;
            }
        }
    }
    __syncthreads();

    // ---- stage D ----
    {
        float bb = r1_b2[0];
        #pragma unroll
        for (int u2 = 0; u2 < 2; ++u2){
            int nt = u2*4 + wv;
            int s0 = nt*16 + nn;
            int ty = s0 >> 3, tx = s0 & 7;
            f32x4 acc = {0,0,0,0};
            #pragma unroll
            for (int ky=0; ky<3; ++ky)
                #pragma unroll
                for (int kx=0; kx<3; ++kx){
                    const int k = ky*3+kx;
                    bf16x8 bfr = lds8(s_t1 + ((ty+ky)*10 + tx+kx)*36 + nQ*8);
                    bf16x8 aw = *(const bf16x8*)(wTr1b + k*512 + nn*32 + nQ*8);
                    acc = MFMA_B16(aw, bfr, acc, 0,0,0);
                }
            if (nQ == 0){
                u8 m = s_m[(ty+3)*14 + tx+3];
                float o = m ? acc[0] + bb : -99.f;
                out1[(size_t)n*HW1 + (y0+ty)*H1 + (x0+tx)] = o;
            }
        }
    }
}

// ---------------- launch ----------------

extern "C" void kernel_launch(void* const* d_in, const int* in_sizes, int n_in,
                              void* d_out, int out_size, void* d_ws, size_t ws_size,
                              hipStream_t stream)
{
    const float* x      = (const float*)d_in[0];
    const float* image  = (const float*)d_in[1];
    const float* masks  = (const float*)d_in[2];
    const float* roi    = (const float*)d_in[3];
    const float* w1a    = (const float*)d_in[4];
    const float* w1b    = (const float*)d_in[5];
    const float* w2a    = (const float*)d_in[6];
    const float* w2b    = (const float*)d_in[7];
    const float* w4a    = (const float*)d_in[8];
    const float* w4b    = (const float*)d_in[9];
    const float* inv4_w = (const float*)d_in[10];
    const float* l4_sub = (const float*)d_in[11];
    const float* inv2_w = (const float*)d_in[12];
    const float* l5_sub = (const float*)d_in[13];
    const float* r4_w1  = (const float*)d_in[14];
    const float* r4_w2  = (const float*)d_in[15];
    const float* r4_b2  = (const float*)d_in[16];
    const float* r1_w1  = (const float*)d_in[17];
    const float* r1_w2  = (const float*)d_in[18];
    const float* r1_b2  = (const float*)d_in[19];
    float* out = (float*)d_out;

    const int N = 8;
    const int H1 = 384, HW1 = 384*384;
    const int H2 = 192, HW2 = 192*192;
    const int H4 = 96,  HW4 = 96*96;

    char* wsp = (char*)d_ws;
    size_t off = 0;
    auto alloc = [&](size_t bytes) -> char* {
        char* p = wsp + off;
        off += (bytes + 255) & ~(size_t)255;
        return p;
    };
    bf16* FEA1 = (bf16*)alloc((size_t)N*32*HW1*2);  // interleaved [N][HW1][32]
    u8*   M1   = (u8*)alloc((size_t)N*HW1);
    u8*   M2   = (u8*)alloc((size_t)N*HW2);
    u8*   M4   = (u8*)alloc((size_t)N*HW4);
    bf16* FEA2 = (bf16*)alloc((size_t)N*32*HW2*2);
    bf16* XS   = (bf16*)alloc((size_t)N*64*HW4*2);
    bf16* GU   = (bf16*)alloc((size_t)N*32*HW2*2);
    bf16* HT   = (bf16*)alloc((size_t)N*64*HW4*2);
    short* WT   = (short*)alloc(6*9216*2);
    short* WT4  = (short*)alloc((size_t)129024*2);
    short* WT1a = (short*)alloc(2048*2);
    short* WTh  = (short*)alloc(2*4608*2);
    (void)ws_size; (void)in_sizes; (void)n_in; (void)out_size;

    short* wT1b  = WT;
    short* wTi2  = WT + 9216;
    short* wTl5  = WT + 2*9216;
    short* wTr1a = WT + 3*9216;
    short* wT2b  = WT + 4*9216;
    short* wT2a  = WT + 5*9216;
    short* wTi4  = WT4;
    short* wT4b  = WT4 + 36864;
    short* wTl4  = WT4 + 73728;
    short* wTr4a = WT4 + 92160;
    short* wT4a  = WT4 + 110592;
    short* wTr1b = WTh;
    short* wTr4b = WTh + 4608;

    dim3 blk(256);

    // masks + weight prep
    k_mask1<<<dim3((N*HW1 + 255)/256), blk, 0, stream>>>(roi, M1, N*HW1);
    k_down<<<dim3((HW2 + 255)/256, N), blk, 0, stream>>>(M1, M2, H1, H1, H2, H2);
    k_down<<<dim3((HW4 + 255)/256, N), blk, 0, stream>>>(M2, M4, H2, H2, H4, H4);
    k_wprep<<<dim3(36, 6), blk, 0, stream>>>(w1b, inv2_w, l5_sub, r1_w1, w2b, w2a, WT);
    k_wprep4<<<dim3(144, 5), blk, 0, stream>>>(inv4_w, w4b, l4_sub, r4_w1, w4a, WT4);
    k_wprep_misc<<<dim3(18, 3), blk, 0, stream>>>(w1a, r1_w2, r4_w2, WT1a, WTh);

    // front
    conv1ab3<<<dim3(1152, 1, N), blk, 0, stream>>>(image, masks, M1, WT1a, wT1b, (short*)FEA1);
    mconv_s2m<32,true><<<dim3(288, 1, N), blk, 0, stream>>>((const short*)FEA1, H1, wT2a, M2, (short*)GU, H2, 12);
    mconv_s1<32,32,0,16><<<dim3(144, 1, N), blk, 0, stream>>>((const short*)GU, H2, wT2b, M2, nullptr, (short*)FEA2, 12);
    mconv_s2m<64,false><<<dim3(72, 1, N), blk, 0, stream>>>((const short*)FEA2, H2, wT4a, M4, (short*)HT, H4, 6);
    mconv_s1<64,64,3,8><<<dim3(72, 1, N), blk, 0, stream>>>((const short*)HT, H4, wT4b, M4, x, (short*)XS, 6);

    // refine_OS4 (8-row tiles: 72 tiles -> 576 blocks)
    mconv_s1<64,32,1,8><<<dim3(72, 1, N), blk, 0, stream>>>((const short*)XS, H4, wTr4a, M4, nullptr, (short*)HT, 6);
    mconv_head32<8><<<dim3(72, 1, N), blk, 0, stream>>>((const short*)HT, H4, wTr4b, r4_b2, M4, out, 6);

    // layer4 fused (MFMA) -> u
    fk_l4c<<<dim3(144, 1, N), blk, 0, stream>>>((const short*)XS, (const short*)FEA2, M2,
                                                wTi4, wTl4, (short*)GU);

    // MFMA back end -> out1
    fk_back8<<<dim3(1152, 1, N), blk, 0, stream>>>((const short*)GU, (const short*)FEA1, M1,
                                                   wTi2, wTl5, wTr1a, wTr1b, r1_b2,
                                                   out + (size_t)N*HW4);
}